// Round 5
// baseline (196.535 us; speedup 1.0000x reference)
//
#include <hip/hip_runtime.h>
#include <hip/hip_bf16.h>
#include <cstddef>

#define B_  8
#define S_  512
#define HID 1024
#define H_  16
#define D_  64

typedef float f32x4 __attribute__((ext_vector_type(4)));
typedef short s16x8 __attribute__((ext_vector_type(8)));
typedef unsigned short u16t;

#define SWZ4(r) (((r) >> 1) & 3)

__device__ __forceinline__ float b2f(u16t u) {
    return __builtin_bit_cast(float, ((unsigned)u) << 16);
}

// f32 -> bf16 hi + bf16 residual lo (both RNE).  x = hi + lo + O(2^-18 x)
__device__ __forceinline__ void split1(float v, u16t& h, u16t& l) {
    unsigned u = __builtin_bit_cast(unsigned, v);
    unsigned hb = (u + 0x7FFFu + ((u >> 16) & 1u)) & 0xFFFF0000u;
    h = (u16t)(hb >> 16);
    float r = v - __builtin_bit_cast(float, hb);
    unsigned ur = __builtin_bit_cast(unsigned, r);
    unsigned lb = (ur + 0x7FFFu + ((ur >> 16) & 1u)) & 0xFFFF0000u;
    l = (u16t)(lb >> 16);
}

// async global->LDS, 16B per lane.  LDS dest must be wave-uniform base
// (HW writes base + lane*16); global src is per-lane.
__device__ __forceinline__ void gll16(const u16t* g, u16t* l) {
    __builtin_amdgcn_global_load_lds(
        (const __attribute__((address_space(1))) unsigned int*)(const void*)g,
        (__attribute__((address_space(3))) unsigned int*)(void*)l, 16, 0, 0);
}

__global__ __launch_bounds__(256) void conv_split_kernel(
    const float* __restrict__ src, u16t* __restrict__ hi,
    u16t* __restrict__ lo, int n4)
{
    int i = blockIdx.x * 256 + threadIdx.x;
    if (i >= n4) return;
    float4 x = ((const float4*)src)[i];
    ushort4 h, l;
    split1(x.x, h.x, l.x);
    split1(x.y, h.y, l.y);
    split1(x.z, h.z, l.z);
    split1(x.w, h.w, l.w);
    ((ushort4*)hi)[i] = h;
    ((ushort4*)lo)[i] = l;
}

// ---------------------------------------------------------------------------
// QKV projection via bf16-split MFMA.  global_load_lds staging with
// pre-swizzled global source (LDS image == old swizzled layout).
// Q/K epilogue: LDS-transpose + ushort8 vector stores.  V: direct ushort4.
// ---------------------------------------------------------------------------
__global__ __launch_bounds__(256) void qkv_mfma_kernel(
    const u16t* __restrict__ Xhi, const u16t* __restrict__ Xlo,
    const u16t* __restrict__ Whi, const u16t* __restrict__ Wlo,
    const float* __restrict__ bq, const float* __restrict__ bk,
    const float* __restrict__ bv,
    u16t* __restrict__ Qh, u16t* __restrict__ Ql,
    u16t* __restrict__ Kh, u16t* __restrict__ Kl,
    u16t* __restrict__ Vth, u16t* __restrict__ Vtl)
{
    const int which = blockIdx.z;
    const u16t* __restrict__ WhiB = Whi + (size_t)which * (HID * HID);
    const u16t* __restrict__ WloB = Wlo + (size_t)which * (HID * HID);
    const float* __restrict__ bias = (which == 0) ? bq : (which == 1) ? bk : bv;

    __shared__ __align__(16) u16t SM[4 * 4096];   // Ah|Al|Bh|Bl, 8KB each
    u16t* const Ah = SM;
    u16t* const Al = SM + 4096;
    u16t* const Bh = SM + 8192;
    u16t* const Bl = SM + 12288;

    const int tid  = threadIdx.x;
    const int lane = tid & 63;
    const int wv_  = tid >> 6;
    const int wr   = wv_ >> 1;
    const int wc   = wv_ & 1;
    const int m0   = blockIdx.y * 128;
    const int n0   = blockIdx.x * 128;

    f32x4 acc[4][4];
    #pragma unroll
    for (int mi = 0; mi < 4; ++mi)
        #pragma unroll
        for (int ni = 0; ni < 4; ++ni)
            #pragma unroll
            for (int e = 0; e < 4; ++e) acc[mi][ni][e] = 0.0f;

    // staging addressing: lane deposits 16B at LDS (wave_base + lane*16B).
    // global source pre-swizzled so LDS slot s of row r holds chunk s^SWZ4(r).
    const int rowA = wv_ * 16 + (lane >> 2);            // 0..63 (half 0)
    const int chA  = (lane & 3) ^ SWZ4(rowA);           // chunk to fetch
    const int ldsw = wv_ * 512;                         // u16 units, wave base
    const size_t aof = (size_t)(m0 + rowA) * HID + chA * 8;
    const size_t bof = (size_t)(n0 + rowA) * HID + chA * 8;

    // fragment read bases (unchanged layout)
    const int colL = lane & 15;
    const int kg   = lane >> 4;
    const int fswz = kg ^ SWZ4(colL);
    const int abase = (wr * 64 + colL) * 32 + fswz * 8;
    const int bbase = (wc * 64 + colL) * 32 + fswz * 8;

    for (int k0 = 0; k0 < HID; k0 += 32) {
        __syncthreads();   // previous iteration's fragment reads complete
        gll16(&Xhi [aof + k0],            Ah + ldsw);
        gll16(&Xhi [aof + k0 + 64 * HID], Ah + ldsw + 2048);
        gll16(&Xlo [aof + k0],            Al + ldsw);
        gll16(&Xlo [aof + k0 + 64 * HID], Al + ldsw + 2048);
        gll16(&WhiB[bof + k0],            Bh + ldsw);
        gll16(&WhiB[bof + k0 + 64 * HID], Bh + ldsw + 2048);
        gll16(&WloB[bof + k0],            Bl + ldsw);
        gll16(&WloB[bof + k0 + 64 * HID], Bl + ldsw + 2048);
        __syncthreads();   // vmcnt(0) drain before reads (compiler-inserted)

        s16x8 ah[4], fb[4], t4[4];
        #pragma unroll
        for (int mi = 0; mi < 4; ++mi)
            ah[mi] = *(const s16x8*)&Ah[abase + mi * 512];
        #pragma unroll
        for (int ni = 0; ni < 4; ++ni)
            fb[ni] = *(const s16x8*)&Bh[bbase + ni * 512];
        #pragma unroll
        for (int mi = 0; mi < 4; ++mi)
            #pragma unroll
            for (int ni = 0; ni < 4; ++ni)
                acc[mi][ni] = __builtin_amdgcn_mfma_f32_16x16x32_bf16(
                    ah[mi], fb[ni], acc[mi][ni], 0, 0, 0);

        #pragma unroll
        for (int mi = 0; mi < 4; ++mi)
            t4[mi] = *(const s16x8*)&Al[abase + mi * 512];
        #pragma unroll
        for (int mi = 0; mi < 4; ++mi)
            #pragma unroll
            for (int ni = 0; ni < 4; ++ni)
                acc[mi][ni] = __builtin_amdgcn_mfma_f32_16x16x32_bf16(
                    t4[mi], fb[ni], acc[mi][ni], 0, 0, 0);

        #pragma unroll
        for (int ni = 0; ni < 4; ++ni)
            t4[ni] = *(const s16x8*)&Bl[bbase + ni * 512];
        #pragma unroll
        for (int mi = 0; mi < 4; ++mi)
            #pragma unroll
            for (int ni = 0; ni < 4; ++ni)
                acc[mi][ni] = __builtin_amdgcn_mfma_f32_16x16x32_bf16(
                    ah[mi], t4[ni], acc[mi][ni], 0, 0, 0);
    }

    // ---- epilogue.  C/D layout: col=lane&15, row=(lane>>4)*4+reg ----
    if (which == 2) {
        // V: direct transposed store [B,H,D,S], s-contiguous ushort4
        #pragma unroll
        for (int mi = 0; mi < 4; ++mi) {
            #pragma unroll
            for (int ni = 0; ni < 4; ++ni) {
                const int n    = n0 + wc * 64 + ni * 16 + colL;
                const int mrow = m0 + wr * 64 + mi * 16 + kg * 4;
                const float bn = bias[n];
                const int bb = mrow >> 9;
                const int ss = mrow & (S_ - 1);
                const int hh = n >> 6;
                const int dd = n & (D_ - 1);
                ushort4 vh, vl;
                u16t h0, l0;
                split1(acc[mi][ni][0] + bn, h0, l0); vh.x = h0; vl.x = l0;
                split1(acc[mi][ni][1] + bn, h0, l0); vh.y = h0; vl.y = l0;
                split1(acc[mi][ni][2] + bn, h0, l0); vh.z = h0; vl.z = l0;
                split1(acc[mi][ni][3] + bn, h0, l0); vh.w = h0; vl.w = l0;
                const size_t off = (((size_t)bb * H_ + hh) * D_ + dd) * S_ + ss;
                *(ushort4*)&Vth[off] = vh;
                *(ushort4*)&Vtl[off] = vl;
            }
        }
    } else {
        // Q/K: 4 passes through a 32x130 f32 LDS tile, vector ushort8 stores
        u16t* __restrict__ Oh = (which == 0) ? Qh : Kh;
        u16t* __restrict__ Ol = (which == 0) ? Ql : Kl;
        float* LF = (float*)SM;                 // 32*130*4 = 16.6KB < 32KB
        float bn4[4];
        #pragma unroll
        for (int ni = 0; ni < 4; ++ni) bn4[ni] = bias[n0 + wc * 64 + ni * 16 + colL];

        const int er  = tid >> 3;               // 0..31
        const int ecc = (tid & 7) * 16;         // 0..112
        const int ehh = (n0 + ecc) >> 6;
        const int edd = ecc & 63;
        const int mrowE = m0 + (er >> 4) * 64 + (er & 15);

        #pragma unroll
        for (int mi = 0; mi < 4; ++mi) {
            __syncthreads();
            #pragma unroll
            for (int ni = 0; ni < 4; ++ni)
                #pragma unroll
                for (int j = 0; j < 4; ++j)
                    LF[(wr * 16 + kg * 4 + j) * 130 + wc * 64 + ni * 16 + colL] =
                        acc[mi][ni][j] + bn4[ni];
            __syncthreads();

            const int mrow = mrowE + mi * 16;
            const int bb = mrow >> 9;
            const int ss = mrow & (S_ - 1);
            __align__(16) u16t hv[16], lv[16];
            #pragma unroll
            for (int u = 0; u < 16; u += 4) {
                float4 v = *(const float4*)&LF[er * 130 + ecc + u];
                split1(v.x, hv[u + 0], lv[u + 0]);
                split1(v.y, hv[u + 1], lv[u + 1]);
                split1(v.z, hv[u + 2], lv[u + 2]);
                split1(v.w, hv[u + 3], lv[u + 3]);
            }
            const size_t off = (((size_t)bb * H_ + ehh) * S_ + ss) * D_ + edd;
            *(s16x8*)&Oh[off]     = *(const s16x8*)&hv[0];
            *(s16x8*)&Oh[off + 8] = *(const s16x8*)&hv[8];
            *(s16x8*)&Ol[off]     = *(const s16x8*)&lv[0];
            *(s16x8*)&Ol[off + 8] = *(const s16x8*)&lv[8];
        }
    }
}

// ---------------------------------------------------------------------------
// MFMA flash attention (unchanged from round 4).
// ---------------------------------------------------------------------------
__global__ __launch_bounds__(256) void attn_mfma_kernel(
    const u16t* __restrict__ Qhg, const u16t* __restrict__ Qlg,
    const u16t* __restrict__ Khg, const u16t* __restrict__ Klg,
    const u16t* __restrict__ Vhg, const u16t* __restrict__ Vlg,
    const int*  __restrict__ ge,  const float* __restrict__ mask,
    const float* __restrict__ dpk, const float* __restrict__ dpv,
    float* __restrict__ out)
{
    __shared__ __align__(16) u16t Qh_s[64 * 72];
    __shared__ __align__(16) u16t Ql_s[64 * 72];
    __shared__ __align__(16) u16t Kh_s[64 * 72];
    __shared__ __align__(16) u16t Kl_s[64 * 72];
    __shared__ __align__(16) u16t Vh_s[64 * 72];
    __shared__ __align__(16) u16t Vl_s[64 * 72];
    __shared__ __align__(16) u16t P_s[4][2 * 16 * 72];
    __shared__ float ms[64];

    const int tid  = threadIdx.x;
    const int lane = tid & 63;
    const int wq   = tid >> 6;
    const int c    = lane & 15;
    const int g    = lane >> 4;
    const int bid  = blockIdx.x;
    const int bh   = bid >> 3;
    const int q0   = (bid & 7) * 64;
    const int b    = bh >> 4;
    const int h    = bh & (H_ - 1);

    u16t* Pwh = &P_s[wq][0];
    u16t* Pwl = &P_s[wq][16 * 72];

    {
        const int r0 = tid >> 2;
        const int o1 = (tid & 3) * 8;
        const int o2 = o1 + 32;
        const size_t qro = ((size_t)bh * S_ + q0 + r0) * D_;
        *(s16x8*)&Qh_s[r0 * 72 + o1] = *(const s16x8*)&Qhg[qro + o1];
        *(s16x8*)&Qh_s[r0 * 72 + o2] = *(const s16x8*)&Qhg[qro + o2];
        *(s16x8*)&Ql_s[r0 * 72 + o1] = *(const s16x8*)&Qlg[qro + o1];
        *(s16x8*)&Ql_s[r0 * 72 + o2] = *(const s16x8*)&Qlg[qro + o2];
    }
    __syncthreads();

    float tq1 = 0.f, tq2 = 0.f;
    {
        const float d1 = dpk[D_ + lane];
        const float d2 = dpk[2 * D_ + lane];
        for (int r = 0; r < 16; ++r) {
            const int row = wq * 16 + r;
            const float qv = b2f(Qh_s[row * 72 + lane]) + b2f(Ql_s[row * 72 + lane]);
            float a1 = qv * d1, a2 = qv * d2;
            #pragma unroll
            for (int off = 32; off > 0; off >>= 1) {
                a1 += __shfl_xor(a1, off);
                a2 += __shfl_xor(a2, off);
            }
            if (r == c) { tq1 = a1; tq2 = a2; }
        }
    }

    const int aK = c * 72 + g * 8;
    const int bQ = (wq * 16 + c) * 72 + g * 8;
    const int bP = c * 72 + g * 8;
    const size_t geoff = ((size_t)b * S_ + q0 + wq * 16 + c) * S_;

    float mrun = -INFINITY, lrun = 0.f, w1 = 0.f, w2 = 0.f;
    f32x4 ctx4[4];
    #pragma unroll
    for (int mi = 0; mi < 4; ++mi)
        #pragma unroll
        for (int e = 0; e < 4; ++e) ctx4[mi][e] = 0.f;

    for (int kt = 0; kt < S_ / 64; ++kt) {
        const int k0 = kt * 64;
        {
            const int r0 = tid >> 2;
            const int o1 = (tid & 3) * 8;
            const int o2 = o1 + 32;
            const size_t kro = ((size_t)bh * S_ + k0 + r0) * D_;
            const size_t vro = ((size_t)bh * D_ + r0) * S_ + k0;
            *(s16x8*)&Kh_s[r0 * 72 + o1] = *(const s16x8*)&Khg[kro + o1];
            *(s16x8*)&Kh_s[r0 * 72 + o2] = *(const s16x8*)&Khg[kro + o2];
            *(s16x8*)&Kl_s[r0 * 72 + o1] = *(const s16x8*)&Klg[kro + o1];
            *(s16x8*)&Kl_s[r0 * 72 + o2] = *(const s16x8*)&Klg[kro + o2];
            *(s16x8*)&Vh_s[r0 * 72 + o1] = *(const s16x8*)&Vhg[vro + o1];
            *(s16x8*)&Vh_s[r0 * 72 + o2] = *(const s16x8*)&Vhg[vro + o2];
            *(s16x8*)&Vl_s[r0 * 72 + o1] = *(const s16x8*)&Vlg[vro + o1];
            *(s16x8*)&Vl_s[r0 * 72 + o2] = *(const s16x8*)&Vlg[vro + o2];
            if (tid < 16)
                *(float4*)&ms[tid * 4] = *(const float4*)&mask[(size_t)b * S_ + k0 + tid * 4];
        }
        __syncthreads();

        f32x4 s4[4];
        #pragma unroll
        for (int mi = 0; mi < 4; ++mi)
            #pragma unroll
            for (int e = 0; e < 4; ++e) s4[mi][e] = 0.f;

        #pragma unroll
        for (int ks = 0; ks < 2; ++ks) {
            const s16x8 qh_ = *(const s16x8*)&Qh_s[bQ + ks * 32];
            const s16x8 ql_ = *(const s16x8*)&Ql_s[bQ + ks * 32];
            s16x8 kh_[4], kl_[4];
            #pragma unroll
            for (int mi = 0; mi < 4; ++mi) {
                kh_[mi] = *(const s16x8*)&Kh_s[aK + mi * 1152 + ks * 32];
                kl_[mi] = *(const s16x8*)&Kl_s[aK + mi * 1152 + ks * 32];
            }
            #pragma unroll
            for (int mi = 0; mi < 4; ++mi)
                s4[mi] = __builtin_amdgcn_mfma_f32_16x16x32_bf16(kh_[mi], qh_, s4[mi], 0, 0, 0);
            #pragma unroll
            for (int mi = 0; mi < 4; ++mi)
                s4[mi] = __builtin_amdgcn_mfma_f32_16x16x32_bf16(kl_[mi], qh_, s4[mi], 0, 0, 0);
            #pragma unroll
            for (int mi = 0; mi < 4; ++mi)
                s4[mi] = __builtin_amdgcn_mfma_f32_16x16x32_bf16(kh_[mi], ql_, s4[mi], 0, 0, 0);
        }

        float sv[4][4];
        int   gcode[4][4];
        float tmax = -INFINITY;
        #pragma unroll
        for (int mi = 0; mi < 4; ++mi) {
            const int4   gc = *(const int4*)&ge[geoff + k0 + mi * 16 + g * 4];
            const float4 mk = *(const float4*)&ms[mi * 16 + g * 4];
            const int   gg[4] = {gc.x, gc.y, gc.z, gc.w};
            const float mm[4] = {mk.x, mk.y, mk.z, mk.w};
            #pragma unroll
            for (int j = 0; j < 4; ++j) {
                const float t = (gg[j] == 1) ? tq1 : (gg[j] == 2) ? tq2 : 0.f;
                const float x = fmaf(s4[mi][j], 0.125f, t + mm[j]);
                sv[mi][j] = x;
                gcode[mi][j] = gg[j];
                tmax = fmaxf(tmax, x);
            }
        }
        tmax = fmaxf(tmax, __shfl_xor(tmax, 16));
        tmax = fmaxf(tmax, __shfl_xor(tmax, 32));

        const float mn    = fmaxf(mrun, tmax);
        const float alpha = __expf(mrun - mn);
        mrun = mn;

        float rs = 0.f, rb1 = 0.f, rb2 = 0.f;
        #pragma unroll
        for (int mi = 0; mi < 4; ++mi)
            #pragma unroll
            for (int j = 0; j < 4; ++j) {
                const float e = __expf(sv[mi][j] - mn);
                sv[mi][j] = e;
                rs += e;
                rb1 += (gcode[mi][j] == 1) ? e : 0.f;
                rb2 += (gcode[mi][j] == 2) ? e : 0.f;
            }
        rs  += __shfl_xor(rs, 16);  rs  += __shfl_xor(rs, 32);
        rb1 += __shfl_xor(rb1, 16); rb1 += __shfl_xor(rb1, 32);
        rb2 += __shfl_xor(rb2, 16); rb2 += __shfl_xor(rb2, 32);

        lrun = lrun * alpha + rs;
        w1   = w1   * alpha + rb1;
        w2   = w2   * alpha + rb2;
        #pragma unroll
        for (int mi = 0; mi < 4; ++mi) ctx4[mi] *= alpha;

        #pragma unroll
        for (int mi = 0; mi < 4; ++mi) {
            ushort4 ph, pl;
            u16t h0, l0;
            split1(sv[mi][0], h0, l0); ph.x = h0; pl.x = l0;
            split1(sv[mi][1], h0, l0); ph.y = h0; pl.y = l0;
            split1(sv[mi][2], h0, l0); ph.z = h0; pl.z = l0;
            split1(sv[mi][3], h0, l0); ph.w = h0; pl.w = l0;
            *(ushort4*)&Pwh[c * 72 + mi * 16 + g * 4] = ph;
            *(ushort4*)&Pwl[c * 72 + mi * 16 + g * 4] = pl;
        }

        #pragma unroll
        for (int ks = 0; ks < 2; ++ks) {
            const s16x8 ph_ = *(const s16x8*)&Pwh[bP + ks * 32];
            const s16x8 pl_ = *(const s16x8*)&Pwl[bP + ks * 32];
            s16x8 vh_[4], vl_[4];
            #pragma unroll
            for (int mi = 0; mi < 4; ++mi) {
                vh_[mi] = *(const s16x8*)&Vh_s[aK + mi * 1152 + ks * 32];
                vl_[mi] = *(const s16x8*)&Vl_s[aK + mi * 1152 + ks * 32];
            }
            #pragma unroll
            for (int mi = 0; mi < 4; ++mi)
                ctx4[mi] = __builtin_amdgcn_mfma_f32_16x16x32_bf16(vh_[mi], ph_, ctx4[mi], 0, 0, 0);
            #pragma unroll
            for (int mi = 0; mi < 4; ++mi)
                ctx4[mi] = __builtin_amdgcn_mfma_f32_16x16x32_bf16(vl_[mi], ph_, ctx4[mi], 0, 0, 0);
            #pragma unroll
            for (int mi = 0; mi < 4; ++mi)
                ctx4[mi] = __builtin_amdgcn_mfma_f32_16x16x32_bf16(vh_[mi], pl_, ctx4[mi], 0, 0, 0);
        }
        __syncthreads();
    }

    const float inv = 1.0f / lrun;
    float* tb = (float*)&P_s[wq][0];
    #pragma unroll
    for (int mi = 0; mi < 4; ++mi) {
        const float4 dk1 = *(const float4*)&dpv[D_ + mi * 16 + g * 4];
        const float4 dk2 = *(const float4*)&dpv[2 * D_ + mi * 16 + g * 4];
        const float a1[4] = {dk1.x, dk1.y, dk1.z, dk1.w};
        const float a2[4] = {dk2.x, dk2.y, dk2.z, dk2.w};
        #pragma unroll
        for (int j = 0; j < 4; ++j) {
            const float val = (ctx4[mi][j] + w1 * a1[j] + w2 * a2[j]) * inv;
            tb[(mi * 16 + g * 4 + j) * 17 + c] = val;
        }
    }
    __syncthreads();
    #pragma unroll
    for (int qq = 0; qq < 16; ++qq)
        out[((size_t)b * S_ + q0 + wq * 16 + qq) * (H_ * D_) + h * D_ + lane] =
            tb[lane * 17 + qq];
}

extern "C" void kernel_launch(void* const* d_in, const int* in_sizes, int n_in,
                              void* d_out, int out_size, void* d_ws, size_t ws_size,
                              hipStream_t stream)
{
    const float* hs   = (const float*)d_in[0];
    const float* mask = (const float*)d_in[1];
    const int*   ge   = (const int*)d_in[2];
    const float* Wq   = (const float*)d_in[3];
    const float* bq   = (const float*)d_in[4];
    const float* Wk   = (const float*)d_in[5];
    const float* bk   = (const float*)d_in[6];
    const float* Wv   = (const float*)d_in[7];
    const float* bv   = (const float*)d_in[8];
    const float* dpk  = (const float*)d_in[9];
    const float* dpv  = (const float*)d_in[10];
    float* out = (float*)d_out;

    const size_t per = (size_t)B_ * H_ * S_ * D_;   // 4,194,304
    const size_t nX  = (size_t)B_ * S_ * HID;       // 4,194,304
    const size_t nW  = (size_t)HID * HID;           // 1,048,576

    u16t* base = (u16t*)d_ws;
    u16t* Qh  = base;
    u16t* Ql  = Qh  + per;
    u16t* Kh  = Ql  + per;
    u16t* Kl  = Kh  + per;
    u16t* Vth = Kl  + per;
    u16t* Vtl = Vth + per;
    u16t* Xhi = Vtl + per;
    u16t* Xlo = Xhi + nX;
    u16t* Whi = Xlo + nX;
    u16t* Wlo = Whi + 3 * nW;

    conv_split_kernel<<<(int)(nX / 4 / 256), 256, 0, stream>>>(hs, Xhi, Xlo, (int)(nX / 4));
    conv_split_kernel<<<(int)(nW / 4 / 256), 256, 0, stream>>>(Wq, Whi,          Wlo,          (int)(nW / 4));
    conv_split_kernel<<<(int)(nW / 4 / 256), 256, 0, stream>>>(Wk, Whi + nW,     Wlo + nW,     (int)(nW / 4));
    conv_split_kernel<<<(int)(nW / 4 / 256), 256, 0, stream>>>(Wv, Whi + 2 * nW, Wlo + 2 * nW, (int)(nW / 4));

    dim3 gridG(HID / 128, (B_ * S_) / 128, 3);
    qkv_mfma_kernel<<<gridG, dim3(256), 0, stream>>>(
        Xhi, Xlo, Whi, Wlo, bq, bk, bv, Qh, Ql, Kh, Kl, Vth, Vtl);

    dim3 gridB(B_ * H_ * (S_ / 64));
    attn_mfma_kernel<<<gridB, dim3(256), 0, stream>>>(
        Qh, Ql, Kh, Kl, Vth, Vtl, ge, mask, dpk, dpv, out);
}

// Round 7
// 170.756 us; speedup vs baseline: 1.1510x; 1.1510x over previous
//
#include <hip/hip_runtime.h>
#include <hip/hip_bf16.h>
#include <cstddef>

#define B_  8
#define S_  512
#define HID 1024
#define H_  16
#define D_  64

typedef float f32x4 __attribute__((ext_vector_type(4)));
typedef _Float16 f16x8 __attribute__((ext_vector_type(8)));
typedef short s16x8 __attribute__((ext_vector_type(8)));
typedef unsigned short u16t;

#define SWZ4(r) (((r) >> 1) & 3)

__device__ __forceinline__ u16t f2h(float v) {
    return __builtin_bit_cast(u16t, (_Float16)v);
}
__device__ __forceinline__ float h2f(u16t u) {
    return (float)__builtin_bit_cast(_Float16, u);
}
// f32 -> fp16 hi + fp16 residual lo.  x = hi + lo + O(2^-22 x)
__device__ __forceinline__ void splitH(float v, u16t& h, u16t& l) {
    _Float16 hh = (_Float16)v;
    _Float16 ll = (_Float16)(v - (float)hh);
    h = __builtin_bit_cast(u16t, hh);
    l = __builtin_bit_cast(u16t, ll);
}

// async global->LDS, 16B per lane (dest = wave base + lane*16)
__device__ __forceinline__ void gll16(const u16t* g, u16t* l) {
    __builtin_amdgcn_global_load_lds(
        (const __attribute__((address_space(1))) unsigned int*)(const void*)g,
        (__attribute__((address_space(3))) unsigned int*)(void*)l, 16, 0, 0);
}

__global__ __launch_bounds__(256) void conv_split_kernel(
    const float* __restrict__ src, u16t* __restrict__ hi,
    u16t* __restrict__ lo, int n4)
{
    int i = blockIdx.x * 256 + threadIdx.x;
    if (i >= n4) return;
    float4 x = ((const float4*)src)[i];
    ushort4 h, l;
    splitH(x.x, h.x, l.x);
    splitH(x.y, h.y, l.y);
    splitH(x.z, h.z, l.z);
    splitH(x.w, h.w, l.w);
    ((ushort4*)hi)[i] = h;
    ((ushort4*)lo)[i] = l;
}

__global__ __launch_bounds__(256) void conv_hi_kernel(
    const float* __restrict__ src, u16t* __restrict__ hi, int n4)
{
    int i = blockIdx.x * 256 + threadIdx.x;
    if (i >= n4) return;
    float4 x = ((const float4*)src)[i];
    ushort4 h;
    h.x = f2h(x.x);
    h.y = f2h(x.y);
    h.z = f2h(x.z);
    h.w = f2h(x.w);
    ((ushort4*)hi)[i] = h;
}

// ---------------------------------------------------------------------------
// QKV projection, fp16 2-term MFMA:  Y = Xhi@Whi^T + Xlo@Whi^T  (+bias).
// Error = fp16 rounding of W only (~1.8e-4 std on outputs).
//   which=0 -> Qh [B,H,S,D] (hi only);  which=1 -> Kh/Kl [B,H,S,D];
//   which=2 -> Vth/Vtl [B,H,D,S] (transposed, PV A-operand).
// ---------------------------------------------------------------------------
__global__ __launch_bounds__(256) void qkv_mfma_kernel(
    const u16t* __restrict__ Xhi, const u16t* __restrict__ Xlo,
    const u16t* __restrict__ Whi,
    const float* __restrict__ bq, const float* __restrict__ bk,
    const float* __restrict__ bv,
    u16t* __restrict__ Qh,
    u16t* __restrict__ Kh, u16t* __restrict__ Kl,
    u16t* __restrict__ Vth, u16t* __restrict__ Vtl)
{
    const int which = blockIdx.z;
    const u16t* __restrict__ WhiB = Whi + (size_t)which * (HID * HID);
    const float* __restrict__ bias = (which == 0) ? bq : (which == 1) ? bk : bv;

    __shared__ __align__(16) u16t SM[3 * 4096];   // Ah|Al|Bh, 8KB each
    u16t* const Ah = SM;
    u16t* const Al = SM + 4096;
    u16t* const Bh = SM + 8192;

    const int tid  = threadIdx.x;
    const int lane = tid & 63;
    const int wv_  = tid >> 6;
    const int wr   = wv_ >> 1;
    const int wc   = wv_ & 1;
    const int m0   = blockIdx.y * 128;
    const int n0   = blockIdx.x * 128;

    f32x4 acc[4][4];
    #pragma unroll
    for (int mi = 0; mi < 4; ++mi)
        #pragma unroll
        for (int ni = 0; ni < 4; ++ni)
            #pragma unroll
            for (int e = 0; e < 4; ++e) acc[mi][ni][e] = 0.0f;

    // staging: lane deposits 16B at (wave base + lane*16); global src
    // pre-swizzled so LDS slot s of row r holds chunk s^SWZ4(r).
    const int rowA = wv_ * 16 + (lane >> 2);
    const int chA  = (lane & 3) ^ SWZ4(rowA);
    const int ldsw = wv_ * 512;
    const size_t aof = (size_t)(m0 + rowA) * HID + chA * 8;
    const size_t bof = (size_t)(n0 + rowA) * HID + chA * 8;

    const int colL = lane & 15;
    const int kg   = lane >> 4;
    const int fswz = kg ^ SWZ4(colL);
    const int abase = (wr * 64 + colL) * 32 + fswz * 8;
    const int bbase = (wc * 64 + colL) * 32 + fswz * 8;

    for (int k0 = 0; k0 < HID; k0 += 32) {
        __syncthreads();
        gll16(&Xhi [aof + k0],            Ah + ldsw);
        gll16(&Xhi [aof + k0 + 64 * HID], Ah + ldsw + 2048);
        gll16(&Xlo [aof + k0],            Al + ldsw);
        gll16(&Xlo [aof + k0 + 64 * HID], Al + ldsw + 2048);
        gll16(&WhiB[bof + k0],            Bh + ldsw);
        gll16(&WhiB[bof + k0 + 64 * HID], Bh + ldsw + 2048);
        __syncthreads();

        f16x8 ah[4], al[4], fb[4];
        #pragma unroll
        for (int mi = 0; mi < 4; ++mi) {
            ah[mi] = *(const f16x8*)&Ah[abase + mi * 512];
            al[mi] = *(const f16x8*)&Al[abase + mi * 512];
        }
        #pragma unroll
        for (int ni = 0; ni < 4; ++ni)
            fb[ni] = *(const f16x8*)&Bh[bbase + ni * 512];
        #pragma unroll
        for (int mi = 0; mi < 4; ++mi)
            #pragma unroll
            for (int ni = 0; ni < 4; ++ni)
                acc[mi][ni] = __builtin_amdgcn_mfma_f32_16x16x32_f16(
                    ah[mi], fb[ni], acc[mi][ni], 0, 0, 0);
        #pragma unroll
        for (int mi = 0; mi < 4; ++mi)
            #pragma unroll
            for (int ni = 0; ni < 4; ++ni)
                acc[mi][ni] = __builtin_amdgcn_mfma_f32_16x16x32_f16(
                    al[mi], fb[ni], acc[mi][ni], 0, 0, 0);
    }

    // ---- epilogue.  C/D layout: col=lane&15, row=(lane>>4)*4+reg ----
    if (which == 2) {
        // V: direct transposed store [B,H,D,S], s-contiguous ushort4 hi+lo
        #pragma unroll
        for (int mi = 0; mi < 4; ++mi) {
            #pragma unroll
            for (int ni = 0; ni < 4; ++ni) {
                const int n    = n0 + wc * 64 + ni * 16 + colL;
                const int mrow = m0 + wr * 64 + mi * 16 + kg * 4;
                const float bn = bias[n];
                const int bb = mrow >> 9;
                const int ss = mrow & (S_ - 1);
                const int hh = n >> 6;
                const int dd = n & (D_ - 1);
                ushort4 vh, vl;
                splitH(acc[mi][ni][0] + bn, vh.x, vl.x);
                splitH(acc[mi][ni][1] + bn, vh.y, vl.y);
                splitH(acc[mi][ni][2] + bn, vh.z, vl.z);
                splitH(acc[mi][ni][3] + bn, vh.w, vl.w);
                const size_t off = (((size_t)bb * H_ + hh) * D_ + dd) * S_ + ss;
                *(ushort4*)&Vth[off] = vh;
                *(ushort4*)&Vtl[off] = vl;
            }
        }
    } else {
        // Q (hi only) / K (hi+lo): LDS f32 transpose + vector ushort8 stores
        float* LF = (float*)SM;                 // 32*130*4 = 16.6KB < 24KB
        float bn4[4];
        #pragma unroll
        for (int ni = 0; ni < 4; ++ni) bn4[ni] = bias[n0 + wc * 64 + ni * 16 + colL];

        const int er  = tid >> 3;               // 0..31
        const int ecc = (tid & 7) * 16;         // 0..112
        const int ehh = (n0 + ecc) >> 6;
        const int edd = ecc & 63;
        const int mrowE = m0 + (er >> 4) * 64 + (er & 15);

        #pragma unroll
        for (int mi = 0; mi < 4; ++mi) {
            __syncthreads();
            #pragma unroll
            for (int ni = 0; ni < 4; ++ni)
                #pragma unroll
                for (int j = 0; j < 4; ++j)
                    LF[(wr * 16 + kg * 4 + j) * 130 + wc * 64 + ni * 16 + colL] =
                        acc[mi][ni][j] + bn4[ni];
            __syncthreads();

            const int mrow = mrowE + mi * 16;
            const int bb = mrow >> 9;
            const int ss = mrow & (S_ - 1);
            __align__(16) u16t hv[16], lv[16];
            #pragma unroll
            for (int u = 0; u < 16; u += 4) {
                float4 v = *(const float4*)&LF[er * 130 + ecc + u];
                splitH(v.x, hv[u + 0], lv[u + 0]);
                splitH(v.y, hv[u + 1], lv[u + 1]);
                splitH(v.z, hv[u + 2], lv[u + 2]);
                splitH(v.w, hv[u + 3], lv[u + 3]);
            }
            const size_t off = (((size_t)bb * H_ + ehh) * S_ + ss) * D_ + edd;
            if (which == 0) {
                *(s16x8*)&Qh[off]     = *(const s16x8*)&hv[0];
                *(s16x8*)&Qh[off + 8] = *(const s16x8*)&hv[8];
            } else {
                *(s16x8*)&Kh[off]     = *(const s16x8*)&hv[0];
                *(s16x8*)&Kh[off + 8] = *(const s16x8*)&hv[8];
                *(s16x8*)&Kl[off]     = *(const s16x8*)&lv[0];
                *(s16x8*)&Kl[off + 8] = *(const s16x8*)&lv[8];
            }
        }
    }
}

// ---------------------------------------------------------------------------
// MFMA flash attention, fp16 2-term.
// Scores transposed: C[k][q] = (Kh+Kl).Qh^T.  PV: ctx^T = (Vh+Vl).Ph^T.
// P stored hi-only.
// P_s is sized 2*16*72 u16 PER WAVE (4608 B) because the epilogue aliases
// each wave's region as a 64x17 f32 transpose buffer (4352 B).  Round 6's
// bug: region was 2304 B -> cross-wave LDS race in the output path.
// ---------------------------------------------------------------------------
__global__ __launch_bounds__(256) void attn_mfma_kernel(
    const u16t* __restrict__ Qhg,
    const u16t* __restrict__ Khg, const u16t* __restrict__ Klg,
    const u16t* __restrict__ Vhg, const u16t* __restrict__ Vlg,
    const int*  __restrict__ ge,  const float* __restrict__ mask,
    const float* __restrict__ dpk, const float* __restrict__ dpv,
    float* __restrict__ out)
{
    __shared__ __align__(16) u16t Qh_s[64 * 72];
    __shared__ __align__(16) u16t Kh_s[64 * 72];
    __shared__ __align__(16) u16t Kl_s[64 * 72];
    __shared__ __align__(16) u16t Vh_s[64 * 72];
    __shared__ __align__(16) u16t Vl_s[64 * 72];
    __shared__ __align__(16) u16t P_s[4][2 * 16 * 72];   // per-wave: P hi (1152) + epilogue f32 headroom
    __shared__ float ms[64];

    const int tid  = threadIdx.x;
    const int lane = tid & 63;
    const int wq   = tid >> 6;
    const int c    = lane & 15;
    const int g    = lane >> 4;
    const int bid  = blockIdx.x;
    const int bh   = bid >> 3;
    const int q0   = (bid & 7) * 64;
    const int b    = bh >> 4;
    const int h    = bh & (H_ - 1);

    u16t* Pw = &P_s[wq][0];

    // ---- stage Q (hi) ----
    {
        const int r0 = tid >> 2;
        const int o1 = (tid & 3) * 8;
        const int o2 = o1 + 32;
        const size_t qro = ((size_t)bh * S_ + q0 + r0) * D_;
        *(s16x8*)&Qh_s[r0 * 72 + o1] = *(const s16x8*)&Qhg[qro + o1];
        *(s16x8*)&Qh_s[r0 * 72 + o2] = *(const s16x8*)&Qhg[qro + o2];
    }
    __syncthreads();

    // ---- t_r = q . dp_k[r] (hi-only q: error ~5e-5, negligible) ----
    float tq1 = 0.f, tq2 = 0.f;
    {
        const float d1 = dpk[D_ + lane];
        const float d2 = dpk[2 * D_ + lane];
        for (int r = 0; r < 16; ++r) {
            const int row = wq * 16 + r;
            const float qv = h2f(Qh_s[row * 72 + lane]);
            float a1 = qv * d1, a2 = qv * d2;
            #pragma unroll
            for (int off = 32; off > 0; off >>= 1) {
                a1 += __shfl_xor(a1, off);
                a2 += __shfl_xor(a2, off);
            }
            if (r == c) { tq1 = a1; tq2 = a2; }
        }
    }

    const int aK = c * 72 + g * 8;
    const int bQ = (wq * 16 + c) * 72 + g * 8;
    const int bP = c * 72 + g * 8;
    const size_t geoff = ((size_t)b * S_ + q0 + wq * 16 + c) * S_;

    float mrun = -INFINITY, lrun = 0.f, w1 = 0.f, w2 = 0.f;
    f32x4 ctx4[4];
    #pragma unroll
    for (int mi = 0; mi < 4; ++mi)
        #pragma unroll
        for (int e = 0; e < 4; ++e) ctx4[mi][e] = 0.f;

    for (int kt = 0; kt < S_ / 64; ++kt) {
        const int k0 = kt * 64;
        {
            const int r0 = tid >> 2;
            const int o1 = (tid & 3) * 8;
            const int o2 = o1 + 32;
            const size_t kro = ((size_t)bh * S_ + k0 + r0) * D_;
            const size_t vro = ((size_t)bh * D_ + r0) * S_ + k0;
            *(s16x8*)&Kh_s[r0 * 72 + o1] = *(const s16x8*)&Khg[kro + o1];
            *(s16x8*)&Kh_s[r0 * 72 + o2] = *(const s16x8*)&Khg[kro + o2];
            *(s16x8*)&Kl_s[r0 * 72 + o1] = *(const s16x8*)&Klg[kro + o1];
            *(s16x8*)&Kl_s[r0 * 72 + o2] = *(const s16x8*)&Klg[kro + o2];
            *(s16x8*)&Vh_s[r0 * 72 + o1] = *(const s16x8*)&Vhg[vro + o1];
            *(s16x8*)&Vh_s[r0 * 72 + o2] = *(const s16x8*)&Vhg[vro + o2];
            *(s16x8*)&Vl_s[r0 * 72 + o1] = *(const s16x8*)&Vlg[vro + o1];
            *(s16x8*)&Vl_s[r0 * 72 + o2] = *(const s16x8*)&Vlg[vro + o2];
            if (tid < 16)
                *(float4*)&ms[tid * 4] = *(const float4*)&mask[(size_t)b * S_ + k0 + tid * 4];
        }
        __syncthreads();

        // ---- QK^T (transposed) ----
        f32x4 s4[4];
        #pragma unroll
        for (int mi = 0; mi < 4; ++mi)
            #pragma unroll
            for (int e = 0; e < 4; ++e) s4[mi][e] = 0.f;

        #pragma unroll
        for (int ks = 0; ks < 2; ++ks) {
            const f16x8 qh_ = *(const f16x8*)&Qh_s[bQ + ks * 32];
            f16x8 kh_[4], kl_[4];
            #pragma unroll
            for (int mi = 0; mi < 4; ++mi) {
                kh_[mi] = *(const f16x8*)&Kh_s[aK + mi * 1152 + ks * 32];
                kl_[mi] = *(const f16x8*)&Kl_s[aK + mi * 1152 + ks * 32];
            }
            #pragma unroll
            for (int mi = 0; mi < 4; ++mi)
                s4[mi] = __builtin_amdgcn_mfma_f32_16x16x32_f16(kh_[mi], qh_, s4[mi], 0, 0, 0);
            #pragma unroll
            for (int mi = 0; mi < 4; ++mi)
                s4[mi] = __builtin_amdgcn_mfma_f32_16x16x32_f16(kl_[mi], qh_, s4[mi], 0, 0, 0);
        }

        // ---- relation lookup + mask + online softmax ----
        float sv[4][4];
        int   gcode[4][4];
        float tmax = -INFINITY;
        #pragma unroll
        for (int mi = 0; mi < 4; ++mi) {
            const int4   gc = *(const int4*)&ge[geoff + k0 + mi * 16 + g * 4];
            const float4 mk = *(const float4*)&ms[mi * 16 + g * 4];
            const int   gg[4] = {gc.x, gc.y, gc.z, gc.w};
            const float mm[4] = {mk.x, mk.y, mk.z, mk.w};
            #pragma unroll
            for (int j = 0; j < 4; ++j) {
                const float t = (gg[j] == 1) ? tq1 : (gg[j] == 2) ? tq2 : 0.f;
                const float x = fmaf(s4[mi][j], 0.125f, t + mm[j]);
                sv[mi][j] = x;
                gcode[mi][j] = gg[j];
                tmax = fmaxf(tmax, x);
            }
        }
        tmax = fmaxf(tmax, __shfl_xor(tmax, 16));
        tmax = fmaxf(tmax, __shfl_xor(tmax, 32));

        const float mn    = fmaxf(mrun, tmax);
        const float alpha = __expf(mrun - mn);
        mrun = mn;

        float rs = 0.f, rb1 = 0.f, rb2 = 0.f;
        #pragma unroll
        for (int mi = 0; mi < 4; ++mi)
            #pragma unroll
            for (int j = 0; j < 4; ++j) {
                const float e = __expf(sv[mi][j] - mn);
                sv[mi][j] = e;
                rs += e;
                rb1 += (gcode[mi][j] == 1) ? e : 0.f;
                rb2 += (gcode[mi][j] == 2) ? e : 0.f;
            }
        rs  += __shfl_xor(rs, 16);  rs  += __shfl_xor(rs, 32);
        rb1 += __shfl_xor(rb1, 16); rb1 += __shfl_xor(rb1, 32);
        rb2 += __shfl_xor(rb2, 16); rb2 += __shfl_xor(rb2, 32);

        lrun = lrun * alpha + rs;
        w1   = w1   * alpha + rb1;
        w2   = w2   * alpha + rb2;
        #pragma unroll
        for (int mi = 0; mi < 4; ++mi) ctx4[mi] *= alpha;

        // ---- P -> fp16 hi, wave-local LDS [q][k] ----
        #pragma unroll
        for (int mi = 0; mi < 4; ++mi) {
            ushort4 ph;
            ph.x = f2h(sv[mi][0]);
            ph.y = f2h(sv[mi][1]);
            ph.z = f2h(sv[mi][2]);
            ph.w = f2h(sv[mi][3]);
            *(ushort4*)&Pw[c * 72 + mi * 16 + g * 4] = ph;
        }

        // ---- PV: ctx^T[d][q] += (Vh+Vl) . P^T ----
        #pragma unroll
        for (int ks = 0; ks < 2; ++ks) {
            const f16x8 ph_ = *(const f16x8*)&Pw[bP + ks * 32];
            f16x8 vh_[4], vl_[4];
            #pragma unroll
            for (int mi = 0; mi < 4; ++mi) {
                vh_[mi] = *(const f16x8*)&Vh_s[aK + mi * 1152 + ks * 32];
                vl_[mi] = *(const f16x8*)&Vl_s[aK + mi * 1152 + ks * 32];
            }
            #pragma unroll
            for (int mi = 0; mi < 4; ++mi)
                ctx4[mi] = __builtin_amdgcn_mfma_f32_16x16x32_f16(vh_[mi], ph_, ctx4[mi], 0, 0, 0);
            #pragma unroll
            for (int mi = 0; mi < 4; ++mi)
                ctx4[mi] = __builtin_amdgcn_mfma_f32_16x16x32_f16(vl_[mi], ph_, ctx4[mi], 0, 0, 0);
        }
        __syncthreads();
    }

    // ---- epilogue: normalize + relation-value; transpose via LDS ----
    const float inv = 1.0f / lrun;
    float* tb = (float*)&P_s[wq][0];   // 64x17 f32 = 4352B <= 4608B per-wave region
    #pragma unroll
    for (int mi = 0; mi < 4; ++mi) {
        const float4 dk1 = *(const float4*)&dpv[D_ + mi * 16 + g * 4];
        const float4 dk2 = *(const float4*)&dpv[2 * D_ + mi * 16 + g * 4];
        const float a1[4] = {dk1.x, dk1.y, dk1.z, dk1.w};
        const float a2[4] = {dk2.x, dk2.y, dk2.z, dk2.w};
        #pragma unroll
        for (int j = 0; j < 4; ++j) {
            const float val = (ctx4[mi][j] + w1 * a1[j] + w2 * a2[j]) * inv;
            tb[(mi * 16 + g * 4 + j) * 17 + c] = val;
        }
    }
    __syncthreads();
    #pragma unroll
    for (int qq = 0; qq < 16; ++qq)
        out[((size_t)b * S_ + q0 + wq * 16 + qq) * (H_ * D_) + h * D_ + lane] =
            tb[lane * 17 + qq];
}

extern "C" void kernel_launch(void* const* d_in, const int* in_sizes, int n_in,
                              void* d_out, int out_size, void* d_ws, size_t ws_size,
                              hipStream_t stream)
{
    const float* hs   = (const float*)d_in[0];
    const float* mask = (const float*)d_in[1];
    const int*   ge   = (const int*)d_in[2];
    const float* Wq   = (const float*)d_in[3];
    const float* bq   = (const float*)d_in[4];
    const float* Wk   = (const float*)d_in[5];
    const float* bk   = (const float*)d_in[6];
    const float* Wv   = (const float*)d_in[7];
    const float* bv   = (const float*)d_in[8];
    const float* dpk  = (const float*)d_in[9];
    const float* dpv  = (const float*)d_in[10];
    float* out = (float*)d_out;

    const size_t per = (size_t)B_ * H_ * S_ * D_;   // 4,194,304
    const size_t nX  = (size_t)B_ * S_ * HID;       // 4,194,304
    const size_t nW  = (size_t)HID * HID;           // 1,048,576

    u16t* base = (u16t*)d_ws;
    u16t* Qh  = base;
    u16t* Kh  = Qh  + per;
    u16t* Kl  = Kh  + per;
    u16t* Vth = Kl  + per;
    u16t* Vtl = Vth + per;
    u16t* Xhi = Vtl + per;
    u16t* Xlo = Xhi + nX;
    u16t* Whi = Xlo + nX;

    conv_split_kernel<<<(int)(nX / 4 / 256), 256, 0, stream>>>(hs, Xhi, Xlo, (int)(nX / 4));
    conv_hi_kernel<<<(int)(nW / 4 / 256), 256, 0, stream>>>(Wq, Whi,          (int)(nW / 4));
    conv_hi_kernel<<<(int)(nW / 4 / 256), 256, 0, stream>>>(Wk, Whi + nW,     (int)(nW / 4));
    conv_hi_kernel<<<(int)(nW / 4 / 256), 256, 0, stream>>>(Wv, Whi + 2 * nW, (int)(nW / 4));

    dim3 gridG(HID / 128, (B_ * S_) / 128, 3);
    qkv_mfma_kernel<<<gridG, dim3(256), 0, stream>>>(
        Xhi, Xlo, Whi, bq, bk, bv, Qh, Kh, Kl, Vth, Vtl);

    dim3 gridB(B_ * H_ * (S_ / 64));
    attn_mfma_kernel<<<gridB, dim3(256), 0, stream>>>(
        Qh, Kh, Kl, Vth, Vtl, ge, mask, dpk, dpv, out);
}

// Round 8
// 111.083 us; speedup vs baseline: 1.7693x; 1.5372x over previous
//
#include <hip/hip_runtime.h>
#include <hip/hip_bf16.h>
#include <cstddef>

#define B_  8
#define S_  512
#define HID 1024
#define H_  16
#define D_  64

typedef float f32x4 __attribute__((ext_vector_type(4)));
typedef _Float16 f16x8 __attribute__((ext_vector_type(8)));
typedef short s16x8 __attribute__((ext_vector_type(8)));
typedef unsigned short u16t;

__device__ __forceinline__ u16t f2h(float v) {
    return __builtin_bit_cast(u16t, (_Float16)v);
}
__device__ __forceinline__ float h2f(u16t u) {
    return (float)__builtin_bit_cast(_Float16, u);
}

// async global->LDS, 16B per lane (dest = wave-uniform base + lane*16)
__device__ __forceinline__ void gll16(const u16t* g, u16t* l) {
    __builtin_amdgcn_global_load_lds(
        (const __attribute__((address_space(1))) unsigned int*)(const void*)g,
        (__attribute__((address_space(3))) unsigned int*)(void*)l, 16, 0, 0);
}

__global__ __launch_bounds__(256) void conv_hi_kernel(
    const float* __restrict__ src, u16t* __restrict__ hi, int n4)
{
    int i = blockIdx.x * 256 + threadIdx.x;
    if (i >= n4) return;
    float4 x = ((const float4*)src)[i];
    ushort4 h;
    h.x = f2h(x.x);
    h.y = f2h(x.y);
    h.z = f2h(x.z);
    h.w = f2h(x.w);
    ((ushort4*)hi)[i] = h;
}

// ---------------------------------------------------------------------------
// QKV projection, pure fp16 MFMA:  Y = Xh@Wh^T + bias (f32 accum).
// Error budget: ~1.4e-4 std per output (X and W fp16 rounding), ok vs 3.3e-3.
// BK=64: Ah/Bh 128x64 fp16 (16KB each), 8 global_load_lds + 16 MFMA per
// K-step, 16 K-steps.  Row swizzle: 16B slot ^= (row&7).
//   which=0 -> Qh [B,H,S,D];  which=1 -> Kh [B,H,S,D];
//   which=2 -> Vth [B,H,D,S] (transposed, PV A-operand).
// ---------------------------------------------------------------------------
__global__ __launch_bounds__(256) void qkv_mfma_kernel(
    const u16t* __restrict__ Xhi, const u16t* __restrict__ Whi,
    const float* __restrict__ bq, const float* __restrict__ bk,
    const float* __restrict__ bv,
    u16t* __restrict__ Qh, u16t* __restrict__ Kh, u16t* __restrict__ Vth)
{
    const int which = blockIdx.z;
    const u16t* __restrict__ WhiB = Whi + (size_t)which * (HID * HID);
    const float* __restrict__ bias = (which == 0) ? bq : (which == 1) ? bk : bv;

    __shared__ __align__(16) u16t SM[2 * 8192];   // Ah | Bh, 16KB each
    u16t* const Ah = SM;
    u16t* const Bh = SM + 8192;

    const int tid  = threadIdx.x;
    const int lane = tid & 63;
    const int wv_  = tid >> 6;
    const int wr   = wv_ >> 1;
    const int wc   = wv_ & 1;
    const int m0   = blockIdx.y * 128;
    const int n0   = blockIdx.x * 128;

    f32x4 acc[4][4];
    #pragma unroll
    for (int mi = 0; mi < 4; ++mi)
        #pragma unroll
        for (int ni = 0; ni < 4; ++ni)
            #pragma unroll
            for (int e = 0; e < 4; ++e) acc[mi][ni][e] = 0.0f;

    // staging: sweep s covers rows wv_*32+s*8 .. +8; lane -> (row, slot).
    // LDS linear (lane*16B); global chunk pre-swizzled: ch = slot ^ (row&7).
    const int rowB0 = wv_ * 32 + (lane >> 3);
    const int ch    = (lane & 7) ^ (rowB0 & 7);
    const size_t aof = (size_t)(m0 + rowB0) * HID + ch * 8;
    const size_t bof = (size_t)(n0 + rowB0) * HID + ch * 8;

    // fragment read bases: row = (wr|wc)*64 + mi*16 + colL, slot=(ks*4+kg)^ (colL&7)
    const int colL = lane & 15;
    const int kg   = lane >> 4;
    const int sx   = colL & 7;
    const int arow = (wr * 64 + colL) * 64;
    const int brow = (wc * 64 + colL) * 64;

    for (int k0 = 0; k0 < HID; k0 += 64) {
        __syncthreads();   // previous iteration's fragment reads complete
        #pragma unroll
        for (int s = 0; s < 4; ++s) {
            gll16(&Xhi [aof + k0 + (size_t)(s * 8) * HID], Ah + (wv_ * 32 + s * 8) * 64);
            gll16(&WhiB[bof + k0 + (size_t)(s * 8) * HID], Bh + (wv_ * 32 + s * 8) * 64);
        }
        __syncthreads();   // tiles ready (compiler drains vmcnt before barrier)

        #pragma unroll
        for (int ks = 0; ks < 2; ++ks) {
            const int so = ((ks * 4 + kg) ^ sx) * 8;
            f16x8 a_[4], b_[4];
            #pragma unroll
            for (int mi = 0; mi < 4; ++mi)
                a_[mi] = *(const f16x8*)&Ah[arow + mi * 1024 + so];
            #pragma unroll
            for (int ni = 0; ni < 4; ++ni)
                b_[ni] = *(const f16x8*)&Bh[brow + ni * 1024 + so];
            #pragma unroll
            for (int mi = 0; mi < 4; ++mi)
                #pragma unroll
                for (int ni = 0; ni < 4; ++ni)
                    acc[mi][ni] = __builtin_amdgcn_mfma_f32_16x16x32_f16(
                        a_[mi], b_[ni], acc[mi][ni], 0, 0, 0);
        }
    }

    // ---- epilogue.  C/D layout: col=lane&15, row=(lane>>4)*4+reg ----
    if (which == 2) {
        // V: direct transposed store [B,H,D,S], s-contiguous ushort4
        #pragma unroll
        for (int mi = 0; mi < 4; ++mi) {
            #pragma unroll
            for (int ni = 0; ni < 4; ++ni) {
                const int n    = n0 + wc * 64 + ni * 16 + colL;
                const int mrow = m0 + wr * 64 + mi * 16 + kg * 4;
                const float bn = bias[n];
                const int bb = mrow >> 9;
                const int ss = mrow & (S_ - 1);
                const int hh = n >> 6;
                const int dd = n & (D_ - 1);
                ushort4 vh;
                vh.x = f2h(acc[mi][ni][0] + bn);
                vh.y = f2h(acc[mi][ni][1] + bn);
                vh.z = f2h(acc[mi][ni][2] + bn);
                vh.w = f2h(acc[mi][ni][3] + bn);
                *(ushort4*)&Vth[(((size_t)bb * H_ + hh) * D_ + dd) * S_ + ss] = vh;
            }
        }
    } else {
        // Q / K: LDS f32 transpose + vector ushort8 stores
        u16t* __restrict__ Oh = (which == 0) ? Qh : Kh;
        float* LF = (float*)SM;                 // 32*130*4 = 16.6KB < 32KB
        float bn4[4];
        #pragma unroll
        for (int ni = 0; ni < 4; ++ni) bn4[ni] = bias[n0 + wc * 64 + ni * 16 + colL];

        const int er  = tid >> 3;               // 0..31
        const int ecc = (tid & 7) * 16;         // 0..112
        const int ehh = (n0 + ecc) >> 6;
        const int edd = ecc & 63;
        const int mrowE = m0 + (er >> 4) * 64 + (er & 15);

        #pragma unroll
        for (int mi = 0; mi < 4; ++mi) {
            __syncthreads();
            #pragma unroll
            for (int ni = 0; ni < 4; ++ni)
                #pragma unroll
                for (int j = 0; j < 4; ++j)
                    LF[(wr * 16 + kg * 4 + j) * 130 + wc * 64 + ni * 16 + colL] =
                        acc[mi][ni][j] + bn4[ni];
            __syncthreads();

            const int mrow = mrowE + mi * 16;
            const int bb = mrow >> 9;
            const int ss = mrow & (S_ - 1);
            __align__(16) u16t hv[16];
            #pragma unroll
            for (int u = 0; u < 16; u += 4) {
                float4 v = *(const float4*)&LF[er * 130 + ecc + u];
                hv[u + 0] = f2h(v.x);
                hv[u + 1] = f2h(v.y);
                hv[u + 2] = f2h(v.z);
                hv[u + 3] = f2h(v.w);
            }
            const size_t off = (((size_t)bb * H_ + ehh) * S_ + ss) * D_ + edd;
            *(s16x8*)&Oh[off]     = *(const s16x8*)&hv[0];
            *(s16x8*)&Oh[off + 8] = *(const s16x8*)&hv[8];
        }
    }
}

// ---------------------------------------------------------------------------
// MFMA flash attention, pure fp16 operands (f32 accum / f32 softmax).
// Scores transposed: C[k][q] = Kh.Qh^T; PV: ctx^T[d][q] = Vth.Ph^T.
// P_s per-wave region = 4608B (epilogue aliases as 64x17 f32 = 4352B).
// ---------------------------------------------------------------------------
__global__ __launch_bounds__(256) void attn_mfma_kernel(
    const u16t* __restrict__ Qhg, const u16t* __restrict__ Khg,
    const u16t* __restrict__ Vhg,
    const int*  __restrict__ ge,  const float* __restrict__ mask,
    const float* __restrict__ dpk, const float* __restrict__ dpv,
    float* __restrict__ out)
{
    __shared__ __align__(16) u16t Qh_s[64 * 72];
    __shared__ __align__(16) u16t Kh_s[64 * 72];
    __shared__ __align__(16) u16t Vh_s[64 * 72];
    __shared__ __align__(16) u16t P_s[4][2 * 16 * 72];
    __shared__ float ms[64];

    const int tid  = threadIdx.x;
    const int lane = tid & 63;
    const int wq   = tid >> 6;
    const int c    = lane & 15;
    const int g    = lane >> 4;
    const int bid  = blockIdx.x;
    const int bh   = bid >> 3;
    const int q0   = (bid & 7) * 64;
    const int b    = bh >> 4;
    const int h    = bh & (H_ - 1);

    u16t* Pw = &P_s[wq][0];

    // ---- stage Q ----
    {
        const int r0 = tid >> 2;
        const int o1 = (tid & 3) * 8;
        const int o2 = o1 + 32;
        const size_t qro = ((size_t)bh * S_ + q0 + r0) * D_;
        *(s16x8*)&Qh_s[r0 * 72 + o1] = *(const s16x8*)&Qhg[qro + o1];
        *(s16x8*)&Qh_s[r0 * 72 + o2] = *(const s16x8*)&Qhg[qro + o2];
    }
    __syncthreads();

    // ---- t_r = q . dp_k[r], r=1,2 (row 0 zeroed by reference) ----
    float tq1 = 0.f, tq2 = 0.f;
    {
        const float d1 = dpk[D_ + lane];
        const float d2 = dpk[2 * D_ + lane];
        for (int r = 0; r < 16; ++r) {
            const int row = wq * 16 + r;
            const float qv = h2f(Qh_s[row * 72 + lane]);
            float a1 = qv * d1, a2 = qv * d2;
            #pragma unroll
            for (int off = 32; off > 0; off >>= 1) {
                a1 += __shfl_xor(a1, off);
                a2 += __shfl_xor(a2, off);
            }
            if (r == c) { tq1 = a1; tq2 = a2; }
        }
    }

    const int aK = c * 72 + g * 8;
    const int bQ = (wq * 16 + c) * 72 + g * 8;
    const int bP = c * 72 + g * 8;
    const size_t geoff = ((size_t)b * S_ + q0 + wq * 16 + c) * S_;

    float mrun = -INFINITY, lrun = 0.f, w1 = 0.f, w2 = 0.f;
    f32x4 ctx4[4];
    #pragma unroll
    for (int mi = 0; mi < 4; ++mi)
        #pragma unroll
        for (int e = 0; e < 4; ++e) ctx4[mi][e] = 0.f;

    for (int kt = 0; kt < S_ / 64; ++kt) {
        const int k0 = kt * 64;
        {
            const int r0 = tid >> 2;
            const int o1 = (tid & 3) * 8;
            const int o2 = o1 + 32;
            const size_t kro = ((size_t)bh * S_ + k0 + r0) * D_;
            const size_t vro = ((size_t)bh * D_ + r0) * S_ + k0;
            *(s16x8*)&Kh_s[r0 * 72 + o1] = *(const s16x8*)&Khg[kro + o1];
            *(s16x8*)&Kh_s[r0 * 72 + o2] = *(const s16x8*)&Khg[kro + o2];
            *(s16x8*)&Vh_s[r0 * 72 + o1] = *(const s16x8*)&Vhg[vro + o1];
            *(s16x8*)&Vh_s[r0 * 72 + o2] = *(const s16x8*)&Vhg[vro + o2];
            if (tid < 16)
                *(float4*)&ms[tid * 4] = *(const float4*)&mask[(size_t)b * S_ + k0 + tid * 4];
        }
        __syncthreads();

        // ---- QK^T (transposed) ----
        f32x4 s4[4];
        #pragma unroll
        for (int mi = 0; mi < 4; ++mi)
            #pragma unroll
            for (int e = 0; e < 4; ++e) s4[mi][e] = 0.f;

        #pragma unroll
        for (int ks = 0; ks < 2; ++ks) {
            const f16x8 qh_ = *(const f16x8*)&Qh_s[bQ + ks * 32];
            #pragma unroll
            for (int mi = 0; mi < 4; ++mi) {
                const f16x8 kh_ = *(const f16x8*)&Kh_s[aK + mi * 1152 + ks * 32];
                s4[mi] = __builtin_amdgcn_mfma_f32_16x16x32_f16(kh_, qh_, s4[mi], 0, 0, 0);
            }
        }

        // ---- relation lookup + mask + online softmax ----
        float sv[4][4];
        int   gcode[4][4];
        float tmax = -INFINITY;
        #pragma unroll
        for (int mi = 0; mi < 4; ++mi) {
            const int4   gc = *(const int4*)&ge[geoff + k0 + mi * 16 + g * 4];
            const float4 mk = *(const float4*)&ms[mi * 16 + g * 4];
            const int   gg[4] = {gc.x, gc.y, gc.z, gc.w};
            const float mm[4] = {mk.x, mk.y, mk.z, mk.w};
            #pragma unroll
            for (int j = 0; j < 4; ++j) {
                const float t = (gg[j] == 1) ? tq1 : (gg[j] == 2) ? tq2 : 0.f;
                const float x = fmaf(s4[mi][j], 0.125f, t + mm[j]);
                sv[mi][j] = x;
                gcode[mi][j] = gg[j];
                tmax = fmaxf(tmax, x);
            }
        }
        tmax = fmaxf(tmax, __shfl_xor(tmax, 16));
        tmax = fmaxf(tmax, __shfl_xor(tmax, 32));

        const float mn    = fmaxf(mrun, tmax);
        const float alpha = __expf(mrun - mn);
        mrun = mn;

        float rs = 0.f, rb1 = 0.f, rb2 = 0.f;
        #pragma unroll
        for (int mi = 0; mi < 4; ++mi)
            #pragma unroll
            for (int j = 0; j < 4; ++j) {
                const float e = __expf(sv[mi][j] - mn);
                sv[mi][j] = e;
                rs += e;
                rb1 += (gcode[mi][j] == 1) ? e : 0.f;
                rb2 += (gcode[mi][j] == 2) ? e : 0.f;
            }
        rs  += __shfl_xor(rs, 16);  rs  += __shfl_xor(rs, 32);
        rb1 += __shfl_xor(rb1, 16); rb1 += __shfl_xor(rb1, 32);
        rb2 += __shfl_xor(rb2, 16); rb2 += __shfl_xor(rb2, 32);

        lrun = lrun * alpha + rs;
        w1   = w1   * alpha + rb1;
        w2   = w2   * alpha + rb2;
        #pragma unroll
        for (int mi = 0; mi < 4; ++mi) ctx4[mi] *= alpha;

        // ---- P -> fp16, wave-local LDS [q][k] ----
        #pragma unroll
        for (int mi = 0; mi < 4; ++mi) {
            ushort4 ph;
            ph.x = f2h(sv[mi][0]);
            ph.y = f2h(sv[mi][1]);
            ph.z = f2h(sv[mi][2]);
            ph.w = f2h(sv[mi][3]);
            *(ushort4*)&Pw[c * 72 + mi * 16 + g * 4] = ph;
        }

        // ---- PV: ctx^T[d][q] += Vth . P^T ----
        #pragma unroll
        for (int ks = 0; ks < 2; ++ks) {
            const f16x8 ph_ = *(const f16x8*)&Pw[bP + ks * 32];
            #pragma unroll
            for (int mi = 0; mi < 4; ++mi) {
                const f16x8 vh_ = *(const f16x8*)&Vh_s[aK + mi * 1152 + ks * 32];
                ctx4[mi] = __builtin_amdgcn_mfma_f32_16x16x32_f16(vh_, ph_, ctx4[mi], 0, 0, 0);
            }
        }
        __syncthreads();
    }

    // ---- epilogue: normalize + relation-value; transpose via LDS ----
    const float inv = 1.0f / lrun;
    float* tb = (float*)&P_s[wq][0];   // 64x17 f32 = 4352B <= 4608B per-wave
    #pragma unroll
    for (int mi = 0; mi < 4; ++mi) {
        const float4 dk1 = *(const float4*)&dpv[D_ + mi * 16 + g * 4];
        const float4 dk2 = *(const float4*)&dpv[2 * D_ + mi * 16 + g * 4];
        const float a1[4] = {dk1.x, dk1.y, dk1.z, dk1.w};
        const float a2[4] = {dk2.x, dk2.y, dk2.z, dk2.w};
        #pragma unroll
        for (int j = 0; j < 4; ++j) {
            const float val = (ctx4[mi][j] + w1 * a1[j] + w2 * a2[j]) * inv;
            tb[(mi * 16 + g * 4 + j) * 17 + c] = val;
        }
    }
    __syncthreads();
    #pragma unroll
    for (int qq = 0; qq < 16; ++qq)
        out[((size_t)b * S_ + q0 + wq * 16 + qq) * (H_ * D_) + h * D_ + lane] =
            tb[lane * 17 + qq];
}

extern "C" void kernel_launch(void* const* d_in, const int* in_sizes, int n_in,
                              void* d_out, int out_size, void* d_ws, size_t ws_size,
                              hipStream_t stream)
{
    const float* hs   = (const float*)d_in[0];
    const float* mask = (const float*)d_in[1];
    const int*   ge   = (const int*)d_in[2];
    const float* Wq   = (const float*)d_in[3];
    const float* bq   = (const float*)d_in[4];
    const float* Wk   = (const float*)d_in[5];
    const float* bk   = (const float*)d_in[6];
    const float* Wv   = (const float*)d_in[7];
    const float* bv   = (const float*)d_in[8];
    const float* dpk  = (const float*)d_in[9];
    const float* dpv  = (const float*)d_in[10];
    float* out = (float*)d_out;

    const size_t per = (size_t)B_ * H_ * S_ * D_;   // 4,194,304
    const size_t nX  = (size_t)B_ * S_ * HID;       // 4,194,304
    const size_t nW  = (size_t)HID * HID;           // 1,048,576

    u16t* base = (u16t*)d_ws;
    u16t* Qh  = base;
    u16t* Kh  = Qh  + per;
    u16t* Vth = Kh  + per;
    u16t* Xhi = Vth + per;
    u16t* Whi = Xhi + nX;

    conv_hi_kernel<<<(int)(nX / 4 / 256), 256, 0, stream>>>(hs, Xhi, (int)(nX / 4));
    conv_hi_kernel<<<(int)(nW / 4 / 256), 256, 0, stream>>>(Wq, Whi,          (int)(nW / 4));
    conv_hi_kernel<<<(int)(nW / 4 / 256), 256, 0, stream>>>(Wk, Whi + nW,     (int)(nW / 4));
    conv_hi_kernel<<<(int)(nW / 4 / 256), 256, 0, stream>>>(Wv, Whi + 2 * nW, (int)(nW / 4));

    dim3 gridG(HID / 128, (B_ * S_) / 128, 3);
    qkv_mfma_kernel<<<gridG, dim3(256), 0, stream>>>(
        Xhi, Whi, bq, bk, bv, Qh, Kh, Vth);

    dim3 gridB(B_ * H_ * (S_ / 64));
    attn_mfma_kernel<<<gridB, dim3(256), 0, stream>>>(
        Qh, Kh, Vth, ge, mask, dpk, dpv, out);
}

// Round 9
// 94.132 us; speedup vs baseline: 2.0879x; 1.1801x over previous
//
#include <hip/hip_runtime.h>
#include <hip/hip_bf16.h>
#include <cstddef>

#define B_  8
#define S_  512
#define HID 1024
#define H_  16
#define D_  64

typedef float f32x4 __attribute__((ext_vector_type(4)));
typedef _Float16 f16x8 __attribute__((ext_vector_type(8)));
typedef short s16x8 __attribute__((ext_vector_type(8)));
typedef unsigned short u16t;

__device__ __forceinline__ u16t f2h(float v) {
    return __builtin_bit_cast(u16t, (_Float16)v);
}
__device__ __forceinline__ float h2f(u16t u) {
    return (float)__builtin_bit_cast(_Float16, u);
}

// async global->LDS, 16B per lane (dest = wave-uniform base + lane*16)
__device__ __forceinline__ void gll16(const u16t* g, u16t* l) {
    __builtin_amdgcn_global_load_lds(
        (const __attribute__((address_space(1))) unsigned int*)(const void*)g,
        (__attribute__((address_space(3))) unsigned int*)(void*)l, 16, 0, 0);
}

// one fused conversion kernel: X (f32->fp16) then Wq,Wk,Wv
__global__ __launch_bounds__(256) void conv_all_kernel(
    const float* __restrict__ X,
    const float* __restrict__ Wq, const float* __restrict__ Wk,
    const float* __restrict__ Wv,
    u16t* __restrict__ Xh, u16t* __restrict__ Wh)
{
    const int nX4 = (B_ * S_ * HID) / 4;     // 1,048,576
    const int nW4 = (HID * HID) / 4;         // 262,144
    int i = blockIdx.x * 256 + threadIdx.x;
    const float* src;
    u16t* dst;
    int off;
    if (i < nX4)                { src = X;  dst = Xh;                        off = i; }
    else if (i < nX4 + nW4)     { src = Wq; dst = Wh;                        off = i - nX4; }
    else if (i < nX4 + 2 * nW4) { src = Wk; dst = Wh + (size_t)HID * HID;    off = i - nX4 - nW4; }
    else                        { src = Wv; dst = Wh + (size_t)2 * HID * HID; off = i - nX4 - 2 * nW4; }
    float4 x = ((const float4*)src)[off];
    ushort4 h;
    h.x = f2h(x.x);
    h.y = f2h(x.y);
    h.z = f2h(x.z);
    h.w = f2h(x.w);
    ((ushort4*)dst)[off] = h;
}

// ---------------------------------------------------------------------------
// QKV projection, pure fp16 MFMA (unchanged from round 8).
// ---------------------------------------------------------------------------
__global__ __launch_bounds__(256) void qkv_mfma_kernel(
    const u16t* __restrict__ Xhi, const u16t* __restrict__ Whi,
    const float* __restrict__ bq, const float* __restrict__ bk,
    const float* __restrict__ bv,
    u16t* __restrict__ Qh, u16t* __restrict__ Kh, u16t* __restrict__ Vth)
{
    const int which = blockIdx.z;
    const u16t* __restrict__ WhiB = Whi + (size_t)which * (HID * HID);
    const float* __restrict__ bias = (which == 0) ? bq : (which == 1) ? bk : bv;

    __shared__ __align__(16) u16t SM[2 * 8192];   // Ah | Bh, 16KB each
    u16t* const Ah = SM;
    u16t* const Bh = SM + 8192;

    const int tid  = threadIdx.x;
    const int lane = tid & 63;
    const int wv_  = tid >> 6;
    const int wr   = wv_ >> 1;
    const int wc   = wv_ & 1;
    const int m0   = blockIdx.y * 128;
    const int n0   = blockIdx.x * 128;

    f32x4 acc[4][4];
    #pragma unroll
    for (int mi = 0; mi < 4; ++mi)
        #pragma unroll
        for (int ni = 0; ni < 4; ++ni)
            #pragma unroll
            for (int e = 0; e < 4; ++e) acc[mi][ni][e] = 0.0f;

    const int rowB0 = wv_ * 32 + (lane >> 3);
    const int ch    = (lane & 7) ^ (rowB0 & 7);
    const size_t aof = (size_t)(m0 + rowB0) * HID + ch * 8;
    const size_t bof = (size_t)(n0 + rowB0) * HID + ch * 8;

    const int colL = lane & 15;
    const int kg   = lane >> 4;
    const int sx   = colL & 7;
    const int arow = (wr * 64 + colL) * 64;
    const int brow = (wc * 64 + colL) * 64;

    for (int k0 = 0; k0 < HID; k0 += 64) {
        __syncthreads();
        #pragma unroll
        for (int s = 0; s < 4; ++s) {
            gll16(&Xhi [aof + k0 + (size_t)(s * 8) * HID], Ah + (wv_ * 32 + s * 8) * 64);
            gll16(&WhiB[bof + k0 + (size_t)(s * 8) * HID], Bh + (wv_ * 32 + s * 8) * 64);
        }
        __syncthreads();

        #pragma unroll
        for (int ks = 0; ks < 2; ++ks) {
            const int so = ((ks * 4 + kg) ^ sx) * 8;
            f16x8 a_[4], b_[4];
            #pragma unroll
            for (int mi = 0; mi < 4; ++mi)
                a_[mi] = *(const f16x8*)&Ah[arow + mi * 1024 + so];
            #pragma unroll
            for (int ni = 0; ni < 4; ++ni)
                b_[ni] = *(const f16x8*)&Bh[brow + ni * 1024 + so];
            #pragma unroll
            for (int mi = 0; mi < 4; ++mi)
                #pragma unroll
                for (int ni = 0; ni < 4; ++ni)
                    acc[mi][ni] = __builtin_amdgcn_mfma_f32_16x16x32_f16(
                        a_[mi], b_[ni], acc[mi][ni], 0, 0, 0);
        }
    }

    if (which == 2) {
        #pragma unroll
        for (int mi = 0; mi < 4; ++mi) {
            #pragma unroll
            for (int ni = 0; ni < 4; ++ni) {
                const int n    = n0 + wc * 64 + ni * 16 + colL;
                const int mrow = m0 + wr * 64 + mi * 16 + kg * 4;
                const float bn = bias[n];
                const int bb = mrow >> 9;
                const int ss = mrow & (S_ - 1);
                const int hh = n >> 6;
                const int dd = n & (D_ - 1);
                ushort4 vh;
                vh.x = f2h(acc[mi][ni][0] + bn);
                vh.y = f2h(acc[mi][ni][1] + bn);
                vh.z = f2h(acc[mi][ni][2] + bn);
                vh.w = f2h(acc[mi][ni][3] + bn);
                *(ushort4*)&Vth[(((size_t)bb * H_ + hh) * D_ + dd) * S_ + ss] = vh;
            }
        }
    } else {
        u16t* __restrict__ Oh = (which == 0) ? Qh : Kh;
        float* LF = (float*)SM;
        float bn4[4];
        #pragma unroll
        for (int ni = 0; ni < 4; ++ni) bn4[ni] = bias[n0 + wc * 64 + ni * 16 + colL];

        const int er  = tid >> 3;
        const int ecc = (tid & 7) * 16;
        const int ehh = (n0 + ecc) >> 6;
        const int edd = ecc & 63;
        const int mrowE = m0 + (er >> 4) * 64 + (er & 15);

        #pragma unroll
        for (int mi = 0; mi < 4; ++mi) {
            __syncthreads();
            #pragma unroll
            for (int ni = 0; ni < 4; ++ni)
                #pragma unroll
                for (int j = 0; j < 4; ++j)
                    LF[(wr * 16 + kg * 4 + j) * 130 + wc * 64 + ni * 16 + colL] =
                        acc[mi][ni][j] + bn4[ni];
            __syncthreads();

            const int mrow = mrowE + mi * 16;
            const int bb = mrow >> 9;
            const int ss = mrow & (S_ - 1);
            __align__(16) u16t hv[16];
            #pragma unroll
            for (int u = 0; u < 16; u += 4) {
                float4 v = *(const float4*)&LF[er * 130 + ecc + u];
                hv[u + 0] = f2h(v.x);
                hv[u + 1] = f2h(v.y);
                hv[u + 2] = f2h(v.z);
                hv[u + 3] = f2h(v.w);
            }
            const size_t off = (((size_t)bb * H_ + ehh) * S_ + ss) * D_ + edd;
            *(s16x8*)&Oh[off]     = *(const s16x8*)&hv[0];
            *(s16x8*)&Oh[off + 8] = *(const s16x8*)&hv[8];
        }
    }
}

// ---------------------------------------------------------------------------
// MFMA flash attention v2: 8 waves / 512 threads / 128 q-rows per block.
// K/V staged once per 128 q-rows (was 64): 1 chunk per thread per tile.
// Q/K/V tiles: pitch 64 u16 + XOR slot swizzle (slot ^= row&7) -> conflict-
// free staging writes AND fragment reads.  P: per-wave [16][72] (unchanged).
// Numerics identical to round 8 (same k-tile order) -> absmax should match.
// ---------------------------------------------------------------------------
__global__ __launch_bounds__(512) void attn_mfma_kernel(
    const u16t* __restrict__ Qhg, const u16t* __restrict__ Khg,
    const u16t* __restrict__ Vhg,
    const int*  __restrict__ ge,  const float* __restrict__ mask,
    const float* __restrict__ dpk, const float* __restrict__ dpv,
    float* __restrict__ out)
{
    __shared__ __align__(16) u16t Q_s[128 * 64];   // 16 KB
    __shared__ __align__(16) u16t K_s[64 * 64];    // 8 KB
    __shared__ __align__(16) u16t V_s[64 * 64];    // 8 KB
    __shared__ __align__(16) u16t P_s[8 * 2304];   // 36 KB: per-wave P(1152)+epilogue f32
    __shared__ float ms[64];

    const int tid  = threadIdx.x;
    const int lane = tid & 63;
    const int wq   = tid >> 6;       // 0..7
    const int c    = lane & 15;
    const int g    = lane >> 4;
    const int sx   = c & 7;
    const int bid  = blockIdx.x;
    const int bh   = bid >> 2;
    const int q0   = (bid & 3) * 128;
    const int b    = bh >> 4;
    const int h    = bh & (H_ - 1);

    u16t* Pw = &P_s[wq * 2304];

    // ---- stage Q: 1024 chunks of 16B, 2 per thread, swizzled ----
    {
        const u16t* qbase = Qhg + ((size_t)bh * S_ + q0) * D_;
        #pragma unroll
        for (int t = 0; t < 2; ++t) {
            const int chk = tid + t * 512;
            const int r = chk >> 3, s = chk & 7;
            *(s16x8*)&Q_s[r * 64 + ((s ^ (r & 7)) << 3)] =
                *(const s16x8*)&qbase[chk * 8];
        }
    }
    __syncthreads();

    // ---- t_r = q . dp_k[r], r=1,2 (row 0 zeroed by reference) ----
    float tq1 = 0.f, tq2 = 0.f;
    {
        const float d1 = dpk[D_ + lane];
        const float d2 = dpk[2 * D_ + lane];
        const int sl = lane >> 3, il = lane & 7;
        for (int r = 0; r < 16; ++r) {
            const int row = wq * 16 + r;
            const float qv = h2f(Q_s[row * 64 + ((sl ^ (row & 7)) << 3) + il]);
            float a1 = qv * d1, a2 = qv * d2;
            #pragma unroll
            for (int off = 32; off > 0; off >>= 1) {
                a1 += __shfl_xor(a1, off);
                a2 += __shfl_xor(a2, off);
            }
            if (r == c) { tq1 = a1; tq2 = a2; }
        }
    }

    const size_t geoff = ((size_t)b * S_ + q0 + wq * 16 + c) * S_;

    float mrun = -INFINITY, lrun = 0.f, w1 = 0.f, w2 = 0.f;
    f32x4 ctx4[4];
    #pragma unroll
    for (int mi = 0; mi < 4; ++mi)
        #pragma unroll
        for (int e = 0; e < 4; ++e) ctx4[mi][e] = 0.f;

    for (int kt = 0; kt < S_ / 64; ++kt) {
        const int k0 = kt * 64;

        // ---- stage K/V tile: 1 chunk per thread each, swizzled ----
        {
            const int r = tid >> 3, s = tid & 7;
            const int ldso = r * 64 + ((s ^ (r & 7)) << 3);
            *(s16x8*)&K_s[ldso] =
                *(const s16x8*)&Khg[((size_t)bh * S_ + k0 + r) * D_ + s * 8];
            *(s16x8*)&V_s[ldso] =
                *(const s16x8*)&Vhg[((size_t)bh * D_ + r) * S_ + k0 + s * 8];
            if (tid < 16)
                *(float4*)&ms[tid * 4] = *(const float4*)&mask[(size_t)b * S_ + k0 + tid * 4];
        }
        __syncthreads();

        // ---- QK^T (transposed): C[k][q], lane holds k=mi*16+g*4+j, q=c ----
        f32x4 s4[4];
        #pragma unroll
        for (int mi = 0; mi < 4; ++mi)
            #pragma unroll
            for (int e = 0; e < 4; ++e) s4[mi][e] = 0.f;

        #pragma unroll
        for (int ks = 0; ks < 2; ++ks) {
            const int so = ((g + 4 * ks) ^ sx) << 3;
            const f16x8 qh_ = *(const f16x8*)&Q_s[(wq * 16 + c) * 64 + so];
            #pragma unroll
            for (int mi = 0; mi < 4; ++mi) {
                const f16x8 kh_ = *(const f16x8*)&K_s[(mi * 16 + c) * 64 + so];
                s4[mi] = __builtin_amdgcn_mfma_f32_16x16x32_f16(kh_, qh_, s4[mi], 0, 0, 0);
            }
        }

        // ---- relation lookup + mask + online softmax ----
        float sv[4][4];
        int   gcode[4][4];
        float tmax = -INFINITY;
        #pragma unroll
        for (int mi = 0; mi < 4; ++mi) {
            const int4   gc = *(const int4*)&ge[geoff + k0 + mi * 16 + g * 4];
            const float4 mk = *(const float4*)&ms[mi * 16 + g * 4];
            const int   gg[4] = {gc.x, gc.y, gc.z, gc.w};
            const float mm[4] = {mk.x, mk.y, mk.z, mk.w};
            #pragma unroll
            for (int j = 0; j < 4; ++j) {
                const float t = (gg[j] == 1) ? tq1 : (gg[j] == 2) ? tq2 : 0.f;
                const float x = fmaf(s4[mi][j], 0.125f, t + mm[j]);
                sv[mi][j] = x;
                gcode[mi][j] = gg[j];
                tmax = fmaxf(tmax, x);
            }
        }
        tmax = fmaxf(tmax, __shfl_xor(tmax, 16));
        tmax = fmaxf(tmax, __shfl_xor(tmax, 32));

        const float mn    = fmaxf(mrun, tmax);
        const float alpha = __expf(mrun - mn);
        mrun = mn;

        float rs = 0.f, rb1 = 0.f, rb2 = 0.f;
        #pragma unroll
        for (int mi = 0; mi < 4; ++mi)
            #pragma unroll
            for (int j = 0; j < 4; ++j) {
                const float e = __expf(sv[mi][j] - mn);
                sv[mi][j] = e;
                rs += e;
                rb1 += (gcode[mi][j] == 1) ? e : 0.f;
                rb2 += (gcode[mi][j] == 2) ? e : 0.f;
            }
        rs  += __shfl_xor(rs, 16);  rs  += __shfl_xor(rs, 32);
        rb1 += __shfl_xor(rb1, 16); rb1 += __shfl_xor(rb1, 32);
        rb2 += __shfl_xor(rb2, 16); rb2 += __shfl_xor(rb2, 32);

        lrun = lrun * alpha + rs;
        w1   = w1   * alpha + rb1;
        w2   = w2   * alpha + rb2;
        #pragma unroll
        for (int mi = 0; mi < 4; ++mi) ctx4[mi] *= alpha;

        // ---- P -> fp16, wave-local LDS [q][k] (pitch 72) ----
        #pragma unroll
        for (int mi = 0; mi < 4; ++mi) {
            ushort4 ph;
            ph.x = f2h(sv[mi][0]);
            ph.y = f2h(sv[mi][1]);
            ph.z = f2h(sv[mi][2]);
            ph.w = f2h(sv[mi][3]);
            *(ushort4*)&Pw[c * 72 + mi * 16 + g * 4] = ph;
        }

        // ---- PV: ctx^T[d][q] += V_s . P^T ----
        #pragma unroll
        for (int ks = 0; ks < 2; ++ks) {
            const int so = ((g + 4 * ks) ^ sx) << 3;
            const f16x8 ph_ = *(const f16x8*)&Pw[c * 72 + g * 8 + ks * 32];
            #pragma unroll
            for (int mi = 0; mi < 4; ++mi) {
                const f16x8 vh_ = *(const f16x8*)&V_s[(mi * 16 + c) * 64 + so];
                ctx4[mi] = __builtin_amdgcn_mfma_f32_16x16x32_f16(vh_, ph_, ctx4[mi], 0, 0, 0);
            }
        }
        __syncthreads();   // all K/V reads done before next staging overwrite
    }

    // ---- epilogue: normalize + relation-value; transpose via LDS ----
    const float inv = 1.0f / lrun;
    float* tb = (float*)&P_s[wq * 2304];   // 64x17 f32 = 4352B <= 4608B per-wave
    #pragma unroll
    for (int mi = 0; mi < 4; ++mi) {
        const float4 dk1 = *(const float4*)&dpv[D_ + mi * 16 + g * 4];
        const float4 dk2 = *(const float4*)&dpv[2 * D_ + mi * 16 + g * 4];
        const float a1[4] = {dk1.x, dk1.y, dk1.z, dk1.w};
        const float a2[4] = {dk2.x, dk2.y, dk2.z, dk2.w};
        #pragma unroll
        for (int j = 0; j < 4; ++j) {
            const float val = (ctx4[mi][j] + w1 * a1[j] + w2 * a2[j]) * inv;
            tb[(mi * 16 + g * 4 + j) * 17 + c] = val;
        }
    }
    __syncthreads();
    #pragma unroll
    for (int qq = 0; qq < 16; ++qq)
        out[((size_t)b * S_ + q0 + wq * 16 + qq) * (H_ * D_) + h * D_ + lane] =
            tb[lane * 17 + qq];
}

extern "C" void kernel_launch(void* const* d_in, const int* in_sizes, int n_in,
                              void* d_out, int out_size, void* d_ws, size_t ws_size,
                              hipStream_t stream)
{
    const float* hs   = (const float*)d_in[0];
    const float* mask = (const float*)d_in[1];
    const int*   ge   = (const int*)d_in[2];
    const float* Wq   = (const float*)d_in[3];
    const float* bq   = (const float*)d_in[4];
    const float* Wk   = (const float*)d_in[5];
    const float* bk   = (const float*)d_in[6];
    const float* Wv   = (const float*)d_in[7];
    const float* bv   = (const float*)d_in[8];
    const float* dpk  = (const float*)d_in[9];
    const float* dpv  = (const float*)d_in[10];
    float* out = (float*)d_out;

    const size_t per = (size_t)B_ * H_ * S_ * D_;   // 4,194,304
    const size_t nX  = (size_t)B_ * S_ * HID;       // 4,194,304
    const size_t nW  = (size_t)HID * HID;           // 1,048,576

    u16t* base = (u16t*)d_ws;
    u16t* Qh  = base;
    u16t* Kh  = Qh  + per;
    u16t* Vth = Kh  + per;
    u16t* Xhi = Vth + per;
    u16t* Whi = Xhi + nX;

    const int nConv = (int)((nX + 3 * nW) / 4);     // 1,835,008
    conv_all_kernel<<<nConv / 256, 256, 0, stream>>>(hs, Wq, Wk, Wv, Xhi, Whi);

    dim3 gridG(HID / 128, (B_ * S_) / 128, 3);
    qkv_mfma_kernel<<<gridG, dim3(256), 0, stream>>>(
        Xhi, Whi, bq, bk, bv, Qh, Kh, Vth);

    dim3 gridB(B_ * H_ * (S_ / 128));
    attn_mfma_kernel<<<gridB, dim3(512), 0, stream>>>(
        Qh, Kh, Vth, ge, mask, dpk, dpv, out);
}

// Round 10
// 89.674 us; speedup vs baseline: 2.1917x; 1.0497x over previous
//
#include <hip/hip_runtime.h>
#include <hip/hip_bf16.h>
#include <cstddef>

#define B_  8
#define S_  512
#define HID 1024
#define H_  16
#define D_  64

typedef float f32x4 __attribute__((ext_vector_type(4)));
typedef _Float16 f16x8 __attribute__((ext_vector_type(8)));
typedef short s16x8 __attribute__((ext_vector_type(8)));
typedef unsigned short u16t;

__device__ __forceinline__ u16t f2h(float v) {
    return __builtin_bit_cast(u16t, (_Float16)v);
}
__device__ __forceinline__ float h2f(u16t u) {
    return (float)__builtin_bit_cast(_Float16, u);
}

// async global->LDS, 16B per lane (dest = wave-uniform base + lane*16)
__device__ __forceinline__ void gll16(const u16t* g, u16t* l) {
    __builtin_amdgcn_global_load_lds(
        (const __attribute__((address_space(1))) unsigned int*)(const void*)g,
        (__attribute__((address_space(3))) unsigned int*)(void*)l, 16, 0, 0);
}

// one fused conversion kernel: X (f32->fp16) then Wq,Wk,Wv
__global__ __launch_bounds__(256) void conv_all_kernel(
    const float* __restrict__ X,
    const float* __restrict__ Wq, const float* __restrict__ Wk,
    const float* __restrict__ Wv,
    u16t* __restrict__ Xh, u16t* __restrict__ Wh)
{
    const int nX4 = (B_ * S_ * HID) / 4;
    const int nW4 = (HID * HID) / 4;
    int i = blockIdx.x * 256 + threadIdx.x;
    const float* src;
    u16t* dst;
    int off;
    if (i < nX4)                { src = X;  dst = Xh;                         off = i; }
    else if (i < nX4 + nW4)     { src = Wq; dst = Wh;                         off = i - nX4; }
    else if (i < nX4 + 2 * nW4) { src = Wk; dst = Wh + (size_t)HID * HID;     off = i - nX4 - nW4; }
    else                        { src = Wv; dst = Wh + (size_t)2 * HID * HID; off = i - nX4 - 2 * nW4; }
    float4 x = ((const float4*)src)[off];
    ushort4 h;
    h.x = f2h(x.x);
    h.y = f2h(x.y);
    h.z = f2h(x.z);
    h.w = f2h(x.w);
    ((ushort4*)dst)[off] = h;
}

// ---------------------------------------------------------------------------
// QKV projection, pure fp16 MFMA (unchanged from round 9).
// ---------------------------------------------------------------------------
__global__ __launch_bounds__(256) void qkv_mfma_kernel(
    const u16t* __restrict__ Xhi, const u16t* __restrict__ Whi,
    const float* __restrict__ bq, const float* __restrict__ bk,
    const float* __restrict__ bv,
    u16t* __restrict__ Qh, u16t* __restrict__ Kh, u16t* __restrict__ Vth)
{
    const int which = blockIdx.z;
    const u16t* __restrict__ WhiB = Whi + (size_t)which * (HID * HID);
    const float* __restrict__ bias = (which == 0) ? bq : (which == 1) ? bk : bv;

    __shared__ __align__(16) u16t SM[2 * 8192];   // Ah | Bh, 16KB each
    u16t* const Ah = SM;
    u16t* const Bh = SM + 8192;

    const int tid  = threadIdx.x;
    const int lane = tid & 63;
    const int wv_  = tid >> 6;
    const int wr   = wv_ >> 1;
    const int wc   = wv_ & 1;
    const int m0   = blockIdx.y * 128;
    const int n0   = blockIdx.x * 128;

    f32x4 acc[4][4];
    #pragma unroll
    for (int mi = 0; mi < 4; ++mi)
        #pragma unroll
        for (int ni = 0; ni < 4; ++ni)
            #pragma unroll
            for (int e = 0; e < 4; ++e) acc[mi][ni][e] = 0.0f;

    const int rowB0 = wv_ * 32 + (lane >> 3);
    const int ch    = (lane & 7) ^ (rowB0 & 7);
    const size_t aof = (size_t)(m0 + rowB0) * HID + ch * 8;
    const size_t bof = (size_t)(n0 + rowB0) * HID + ch * 8;

    const int colL = lane & 15;
    const int kg   = lane >> 4;
    const int sx   = colL & 7;
    const int arow = (wr * 64 + colL) * 64;
    const int brow = (wc * 64 + colL) * 64;

    for (int k0 = 0; k0 < HID; k0 += 64) {
        __syncthreads();
        #pragma unroll
        for (int s = 0; s < 4; ++s) {
            gll16(&Xhi [aof + k0 + (size_t)(s * 8) * HID], Ah + (wv_ * 32 + s * 8) * 64);
            gll16(&WhiB[bof + k0 + (size_t)(s * 8) * HID], Bh + (wv_ * 32 + s * 8) * 64);
        }
        __syncthreads();

        #pragma unroll
        for (int ks = 0; ks < 2; ++ks) {
            const int so = ((ks * 4 + kg) ^ sx) * 8;
            f16x8 a_[4], b_[4];
            #pragma unroll
            for (int mi = 0; mi < 4; ++mi)
                a_[mi] = *(const f16x8*)&Ah[arow + mi * 1024 + so];
            #pragma unroll
            for (int ni = 0; ni < 4; ++ni)
                b_[ni] = *(const f16x8*)&Bh[brow + ni * 1024 + so];
            #pragma unroll
            for (int mi = 0; mi < 4; ++mi)
                #pragma unroll
                for (int ni = 0; ni < 4; ++ni)
                    acc[mi][ni] = __builtin_amdgcn_mfma_f32_16x16x32_f16(
                        a_[mi], b_[ni], acc[mi][ni], 0, 0, 0);
        }
    }

    if (which == 2) {
        #pragma unroll
        for (int mi = 0; mi < 4; ++mi) {
            #pragma unroll
            for (int ni = 0; ni < 4; ++ni) {
                const int n    = n0 + wc * 64 + ni * 16 + colL;
                const int mrow = m0 + wr * 64 + mi * 16 + kg * 4;
                const float bn = bias[n];
                const int bb = mrow >> 9;
                const int ss = mrow & (S_ - 1);
                const int hh = n >> 6;
                const int dd = n & (D_ - 1);
                ushort4 vh;
                vh.x = f2h(acc[mi][ni][0] + bn);
                vh.y = f2h(acc[mi][ni][1] + bn);
                vh.z = f2h(acc[mi][ni][2] + bn);
                vh.w = f2h(acc[mi][ni][3] + bn);
                *(ushort4*)&Vth[(((size_t)bb * H_ + hh) * D_ + dd) * S_ + ss] = vh;
            }
        }
    } else {
        u16t* __restrict__ Oh = (which == 0) ? Qh : Kh;
        float* LF = (float*)SM;
        float bn4[4];
        #pragma unroll
        for (int ni = 0; ni < 4; ++ni) bn4[ni] = bias[n0 + wc * 64 + ni * 16 + colL];

        const int er  = tid >> 3;
        const int ecc = (tid & 7) * 16;
        const int ehh = (n0 + ecc) >> 6;
        const int edd = ecc & 63;
        const int mrowE = m0 + (er >> 4) * 64 + (er & 15);

        #pragma unroll
        for (int mi = 0; mi < 4; ++mi) {
            __syncthreads();
            #pragma unroll
            for (int ni = 0; ni < 4; ++ni)
                #pragma unroll
                for (int j = 0; j < 4; ++j)
                    LF[(wr * 16 + kg * 4 + j) * 130 + wc * 64 + ni * 16 + colL] =
                        acc[mi][ni][j] + bn4[ni];
            __syncthreads();

            const int mrow = mrowE + mi * 16;
            const int bb = mrow >> 9;
            const int ss = mrow & (S_ - 1);
            __align__(16) u16t hv[16];
            #pragma unroll
            for (int u = 0; u < 16; u += 4) {
                float4 v = *(const float4*)&LF[er * 130 + ecc + u];
                hv[u + 0] = f2h(v.x);
                hv[u + 1] = f2h(v.y);
                hv[u + 2] = f2h(v.z);
                hv[u + 3] = f2h(v.w);
            }
            const size_t off = (((size_t)bb * H_ + ehh) * S_ + ss) * D_ + edd;
            *(s16x8*)&Oh[off]     = *(const s16x8*)&hv[0];
            *(s16x8*)&Oh[off + 8] = *(const s16x8*)&hv[8];
        }
    }
}

// ---------------------------------------------------------------------------
// MFMA flash attention v3: 8 waves / 128 q-rows per block.
//  - T14 async-STAGE: issue tile kt+1's K/V global loads BEFORE computing
//    tile kt; ds_write them after the post-PV barrier (latency hidden).
//  - parallel t1/t2 prologue (per-lane partial dot + 2 shuffles).
//  - P buffer pitch-64 + XOR slot swizzle (same as K/V) -> conflict-free.
//  - mask read directly from global (L2-resident 16KB), no LDS stage.
// ---------------------------------------------------------------------------
__global__ __launch_bounds__(512) void attn_mfma_kernel(
    const u16t* __restrict__ Qhg, const u16t* __restrict__ Khg,
    const u16t* __restrict__ Vhg,
    const int*  __restrict__ ge,  const float* __restrict__ mask,
    const float* __restrict__ dpk, const float* __restrict__ dpv,
    float* __restrict__ out)
{
    __shared__ __align__(16) u16t Q_s[128 * 64];   // 16 KB
    __shared__ __align__(16) u16t K_s[64 * 64];    // 8 KB
    __shared__ __align__(16) u16t V_s[64 * 64];    // 8 KB
    __shared__ __align__(16) u16t P_s[8 * 2304];   // 36 KB: per-wave P(1024)+epilogue f32(4352B)

    const int tid  = threadIdx.x;
    const int lane = tid & 63;
    const int wq   = tid >> 6;       // 0..7
    const int c    = lane & 15;
    const int g    = lane >> 4;
    const int sx   = c & 7;
    const int bid  = blockIdx.x;
    const int bh   = bid >> 2;
    const int q0   = (bid & 3) * 128;
    const int b    = bh >> 4;
    const int h    = bh & (H_ - 1);

    u16t* Pw = &P_s[wq * 2304];

    // ---- stage Q: 1024 chunks of 16B, 2 per thread, swizzled ----
    {
        const u16t* qbase = Qhg + ((size_t)bh * S_ + q0) * D_;
        #pragma unroll
        for (int t = 0; t < 2; ++t) {
            const int chk = tid + t * 512;
            const int r = chk >> 3, s = chk & 7;
            *(s16x8*)&Q_s[r * 64 + ((s ^ (r & 7)) << 3)] =
                *(const s16x8*)&qbase[chk * 8];
        }
    }

    // K/V staging mapping (1 chunk of 16B each per thread per tile)
    const int r_   = tid >> 3;
    const int s_   = tid & 7;
    const int ldso = r_ * 64 + ((s_ ^ (r_ & 7)) << 3);
    const u16t* kgp = &Khg[((size_t)bh * S_ + r_) * D_ + s_ * 8];
    const u16t* vgp = &Vhg[((size_t)bh * D_ + r_) * S_ + s_ * 8];

    // prologue: tile 0 staged synchronously
    {
        s16x8 kr = *(const s16x8*)kgp;
        s16x8 vr = *(const s16x8*)vgp;
        *(s16x8*)&K_s[ldso] = kr;
        *(s16x8*)&V_s[ldso] = vr;
    }
    __syncthreads();

    // ---- t_r = q . dp_k[r], r=1,2: per-lane partial dot + xor-16/32 ----
    float tq1, tq2;
    {
        const int qrow = wq * 16 + c;
        float a1 = 0.f, a2 = 0.f;
        #pragma unroll
        for (int t = 0; t < 2; ++t) {
            const int slot = 2 * g + t;
            const f16x8 qv8 = *(const f16x8*)&Q_s[qrow * 64 + ((slot ^ sx) << 3)];
            const int dbase = slot * 8;
            #pragma unroll
            for (int i = 0; i < 8; ++i) {
                const float qv = (float)qv8[i];
                a1 = fmaf(qv, dpk[D_ + dbase + i], a1);
                a2 = fmaf(qv, dpk[2 * D_ + dbase + i], a2);
            }
        }
        a1 += __shfl_xor(a1, 16); a1 += __shfl_xor(a1, 32);
        a2 += __shfl_xor(a2, 16); a2 += __shfl_xor(a2, 32);
        tq1 = a1; tq2 = a2;
    }

    const size_t geoff = ((size_t)b * S_ + q0 + wq * 16 + c) * S_;
    const float* mrow = &mask[(size_t)b * S_];

    float mrun = -INFINITY, lrun = 0.f, w1 = 0.f, w2 = 0.f;
    f32x4 ctx4[4];
    #pragma unroll
    for (int mi = 0; mi < 4; ++mi)
        #pragma unroll
        for (int e = 0; e < 4; ++e) ctx4[mi][e] = 0.f;

    for (int kt = 0; kt < S_ / 64; ++kt) {
        const int k0 = kt * 64;

        // ---- T14: issue next tile's loads now; write after the barrier ----
        s16x8 krB, vrB;
        if (kt < S_ / 64 - 1) {
            krB = *(const s16x8*)(kgp + (size_t)(k0 + 64) * D_);
            vrB = *(const s16x8*)(vgp + (k0 + 64));
        }

        // ---- QK^T (transposed): C[k][q], lane holds k=mi*16+g*4+j, q=c ----
        f32x4 s4[4];
        #pragma unroll
        for (int mi = 0; mi < 4; ++mi)
            #pragma unroll
            for (int e = 0; e < 4; ++e) s4[mi][e] = 0.f;

        #pragma unroll
        for (int ks = 0; ks < 2; ++ks) {
            const int so = ((g + 4 * ks) ^ sx) << 3;
            const f16x8 qh_ = *(const f16x8*)&Q_s[(wq * 16 + c) * 64 + so];
            #pragma unroll
            for (int mi = 0; mi < 4; ++mi) {
                const f16x8 kh_ = *(const f16x8*)&K_s[(mi * 16 + c) * 64 + so];
                s4[mi] = __builtin_amdgcn_mfma_f32_16x16x32_f16(kh_, qh_, s4[mi], 0, 0, 0);
            }
        }

        // ---- relation lookup + mask + online softmax ----
        float sv[4][4];
        int   gcode[4][4];
        float tmax = -INFINITY;
        #pragma unroll
        for (int mi = 0; mi < 4; ++mi) {
            const int4   gc = *(const int4*)&ge[geoff + k0 + mi * 16 + g * 4];
            const float4 mk = *(const float4*)&mrow[k0 + mi * 16 + g * 4];
            const int   gg[4] = {gc.x, gc.y, gc.z, gc.w};
            const float mm[4] = {mk.x, mk.y, mk.z, mk.w};
            #pragma unroll
            for (int j = 0; j < 4; ++j) {
                const float t = (gg[j] == 1) ? tq1 : (gg[j] == 2) ? tq2 : 0.f;
                const float x = fmaf(s4[mi][j], 0.125f, t + mm[j]);
                sv[mi][j] = x;
                gcode[mi][j] = gg[j];
                tmax = fmaxf(tmax, x);
            }
        }
        tmax = fmaxf(tmax, __shfl_xor(tmax, 16));
        tmax = fmaxf(tmax, __shfl_xor(tmax, 32));

        const float mn    = fmaxf(mrun, tmax);
        const float alpha = __expf(mrun - mn);
        mrun = mn;

        float rs = 0.f, rb1 = 0.f, rb2 = 0.f;
        #pragma unroll
        for (int mi = 0; mi < 4; ++mi)
            #pragma unroll
            for (int j = 0; j < 4; ++j) {
                const float e = __expf(sv[mi][j] - mn);
                sv[mi][j] = e;
                rs += e;
                rb1 += (gcode[mi][j] == 1) ? e : 0.f;
                rb2 += (gcode[mi][j] == 2) ? e : 0.f;
            }
        rs  += __shfl_xor(rs, 16);  rs  += __shfl_xor(rs, 32);
        rb1 += __shfl_xor(rb1, 16); rb1 += __shfl_xor(rb1, 32);
        rb2 += __shfl_xor(rb2, 16); rb2 += __shfl_xor(rb2, 32);

        lrun = lrun * alpha + rs;
        w1   = w1   * alpha + rb1;
        w2   = w2   * alpha + rb2;
        #pragma unroll
        for (int mi = 0; mi < 4; ++mi) ctx4[mi] *= alpha;

        // ---- P -> fp16, wave-local LDS, pitch 64 + XOR slot swizzle ----
        #pragma unroll
        for (int mi = 0; mi < 4; ++mi) {
            ushort4 ph;
            ph.x = f2h(sv[mi][0]);
            ph.y = f2h(sv[mi][1]);
            ph.z = f2h(sv[mi][2]);
            ph.w = f2h(sv[mi][3]);
            const int slotp = (2 * mi + (g >> 1)) ^ sx;
            *(ushort4*)&Pw[c * 64 + slotp * 8 + (g & 1) * 4] = ph;
        }

        // ---- PV: ctx^T[d][q] += V_s . P^T ----
        #pragma unroll
        for (int ks = 0; ks < 2; ++ks) {
            const int so = ((g + 4 * ks) ^ sx) << 3;
            const f16x8 ph_ = *(const f16x8*)&Pw[c * 64 + so];
            #pragma unroll
            for (int mi = 0; mi < 4; ++mi) {
                const f16x8 vh_ = *(const f16x8*)&V_s[(mi * 16 + c) * 64 + so];
                ctx4[mi] = __builtin_amdgcn_mfma_f32_16x16x32_f16(vh_, ph_, ctx4[mi], 0, 0, 0);
            }
        }
        __syncthreads();   // all K/V reads of this tile done

        if (kt < S_ / 64 - 1) {
            *(s16x8*)&K_s[ldso] = krB;   // vmcnt wait lands here, hidden
            *(s16x8*)&V_s[ldso] = vrB;
            __syncthreads();             // next tile ready
        }
    }

    // ---- epilogue: normalize + relation-value; transpose via LDS ----
    const float inv = 1.0f / lrun;
    float* tb = (float*)&P_s[wq * 2304];   // 64x17 f32 = 4352B <= 4608B per-wave
    #pragma unroll
    for (int mi = 0; mi < 4; ++mi) {
        const float4 dk1 = *(const float4*)&dpv[D_ + mi * 16 + g * 4];
        const float4 dk2 = *(const float4*)&dpv[2 * D_ + mi * 16 + g * 4];
        const float a1[4] = {dk1.x, dk1.y, dk1.z, dk1.w};
        const float a2[4] = {dk2.x, dk2.y, dk2.z, dk2.w};
        #pragma unroll
        for (int j = 0; j < 4; ++j) {
            const float val = (ctx4[mi][j] + w1 * a1[j] + w2 * a2[j]) * inv;
            tb[(mi * 16 + g * 4 + j) * 17 + c] = val;
        }
    }
    __syncthreads();
    #pragma unroll
    for (int qq = 0; qq < 16; ++qq)
        out[((size_t)b * S_ + q0 + wq * 16 + qq) * (H_ * D_) + h * D_ + lane] =
            tb[lane * 17 + qq];
}

extern "C" void kernel_launch(void* const* d_in, const int* in_sizes, int n_in,
                              void* d_out, int out_size, void* d_ws, size_t ws_size,
                              hipStream_t stream)
{
    const float* hs   = (const float*)d_in[0];
    const float* mask = (const float*)d_in[1];
    const int*   ge   = (const int*)d_in[2];
    const float* Wq   = (const float*)d_in[3];
    const float* bq   = (const float*)d_in[4];
    const float* Wk   = (const float*)d_in[5];
    const float* bk   = (const float*)d_in[6];
    const float* Wv   = (const float*)d_in[7];
    const float* bv   = (const float*)d_in[8];
    const float* dpk  = (const float*)d_in[9];
    const float* dpv  = (const float*)d_in[10];
    float* out = (float*)d_out;

    const size_t per = (size_t)B_ * H_ * S_ * D_;   // 4,194,304
    const size_t nX  = (size_t)B_ * S_ * HID;       // 4,194,304
    const size_t nW  = (size_t)HID * HID;           // 1,048,576

    u16t* base = (u16t*)d_ws;
    u16t* Qh  = base;
    u16t* Kh  = Qh  + per;
    u16t* Vth = Kh  + per;
    u16t* Xhi = Vth + per;
    u16t* Whi = Xhi + nX;

    const int nConv = (int)((nX + 3 * nW) / 4);
    conv_all_kernel<<<nConv / 256, 256, 0, stream>>>(hs, Wq, Wk, Wv, Xhi, Whi);

    dim3 gridG(HID / 128, (B_ * S_) / 128, 3);
    qkv_mfma_kernel<<<gridG, dim3(256), 0, stream>>>(
        Xhi, Whi, bq, bk, bv, Qh, Kh, Vth);

    dim3 gridB(B_ * H_ * (S_ / 128));
    attn_mfma_kernel<<<gridB, dim3(512), 0, stream>>>(
        Qh, Kh, Vth, ge, mask, dpk, dpv, out);
}

// Round 11
// 79.647 us; speedup vs baseline: 2.4676x; 1.1259x over previous
//
#include <hip/hip_runtime.h>
#include <hip/hip_bf16.h>
#include <cstddef>

#define B_  8
#define S_  512
#define HID 1024
#define H_  16
#define D_  64

typedef float f32x4 __attribute__((ext_vector_type(4)));
typedef _Float16 f16x8 __attribute__((ext_vector_type(8)));
typedef short s16x8 __attribute__((ext_vector_type(8)));
typedef unsigned short u16t;

__device__ __forceinline__ u16t f2h(float v) {
    return __builtin_bit_cast(u16t, (_Float16)v);
}
__device__ __forceinline__ float h2f(u16t u) {
    return (float)__builtin_bit_cast(_Float16, u);
}

// async global->LDS, 16B per lane (dest = wave-uniform base + lane*16)
__device__ __forceinline__ void gll16(const u16t* g, u16t* l) {
    __builtin_amdgcn_global_load_lds(
        (const __attribute__((address_space(1))) unsigned int*)(const void*)g,
        (__attribute__((address_space(3))) unsigned int*)(void*)l, 16, 0, 0);
}

// one fused conversion kernel: X (f32->fp16) then Wq,Wk,Wv
__global__ __launch_bounds__(256) void conv_all_kernel(
    const float* __restrict__ X,
    const float* __restrict__ Wq, const float* __restrict__ Wk,
    const float* __restrict__ Wv,
    u16t* __restrict__ Xh, u16t* __restrict__ Wh)
{
    const int nX4 = (B_ * S_ * HID) / 4;
    const int nW4 = (HID * HID) / 4;
    int i = blockIdx.x * 256 + threadIdx.x;
    const float* src;
    u16t* dst;
    int off;
    if (i < nX4)                { src = X;  dst = Xh;                         off = i; }
    else if (i < nX4 + nW4)     { src = Wq; dst = Wh;                         off = i - nX4; }
    else if (i < nX4 + 2 * nW4) { src = Wk; dst = Wh + (size_t)HID * HID;     off = i - nX4 - nW4; }
    else                        { src = Wv; dst = Wh + (size_t)2 * HID * HID; off = i - nX4 - 2 * nW4; }
    float4 x = ((const float4*)src)[off];
    ushort4 h;
    h.x = f2h(x.x);
    h.y = f2h(x.y);
    h.z = f2h(x.z);
    h.w = f2h(x.w);
    ((ushort4*)dst)[off] = h;
}

// ---------------------------------------------------------------------------
// QKV projection, pure fp16 MFMA, DOUBLE-BUFFERED K-loop (one barrier/step):
// issue tile k+1's global_load_lds into the alternate 32KB buffer before
// computing tile k; barrier drains the loads after a full compute of cover.
// ---------------------------------------------------------------------------
__global__ __launch_bounds__(256) void qkv_mfma_kernel(
    const u16t* __restrict__ Xhi, const u16t* __restrict__ Whi,
    const float* __restrict__ bq, const float* __restrict__ bk,
    const float* __restrict__ bv,
    u16t* __restrict__ Qh, u16t* __restrict__ Kh, u16t* __restrict__ Vth)
{
    const int which = blockIdx.z;
    const u16t* __restrict__ WhiB = Whi + (size_t)which * (HID * HID);
    const float* __restrict__ bias = (which == 0) ? bq : (which == 1) ? bk : bv;

    // 2 buffers x {Ah(16KB) | Bh(16KB)} = 64KB
    __shared__ __align__(16) u16t SM[2 * 16384];

    const int tid  = threadIdx.x;
    const int lane = tid & 63;
    const int wv_  = tid >> 6;
    const int wr   = wv_ >> 1;
    const int wc   = wv_ & 1;
    const int m0   = blockIdx.y * 128;
    const int n0   = blockIdx.x * 128;

    f32x4 acc[4][4];
    #pragma unroll
    for (int mi = 0; mi < 4; ++mi)
        #pragma unroll
        for (int ni = 0; ni < 4; ++ni)
            #pragma unroll
            for (int e = 0; e < 4; ++e) acc[mi][ni][e] = 0.0f;

    const int rowB0 = wv_ * 32 + (lane >> 3);
    const int ch    = (lane & 7) ^ (rowB0 & 7);
    const size_t aof = (size_t)(m0 + rowB0) * HID + ch * 8;
    const size_t bof = (size_t)(n0 + rowB0) * HID + ch * 8;
    const int ldsA = (wv_ * 32) * 64;        // wave-uniform bases (u16 units)

    const int colL = lane & 15;
    const int kg   = lane >> 4;
    const int sx   = colL & 7;
    const int arow = (wr * 64 + colL) * 64;
    const int brow = (wc * 64 + colL) * 64;

    // prologue: stage tile 0 into buf0
    #pragma unroll
    for (int s = 0; s < 4; ++s) {
        gll16(&Xhi [aof + (size_t)(s * 8) * HID], SM + ldsA + s * 512);
        gll16(&WhiB[bof + (size_t)(s * 8) * HID], SM + 8192 + ldsA + s * 512);
    }
    __syncthreads();

    for (int k0 = 0; k0 < HID; k0 += 64) {
        const int cur = (k0 >> 6) & 1;
        u16t* const bufc = SM + cur * 16384;
        if (k0 + 64 < HID) {
            u16t* const bufn = SM + (cur ^ 1) * 16384;
            #pragma unroll
            for (int s = 0; s < 4; ++s) {
                gll16(&Xhi [aof + k0 + 64 + (size_t)(s * 8) * HID], bufn + ldsA + s * 512);
                gll16(&WhiB[bof + k0 + 64 + (size_t)(s * 8) * HID], bufn + 8192 + ldsA + s * 512);
            }
        }

        #pragma unroll
        for (int ks = 0; ks < 2; ++ks) {
            const int so = ((ks * 4 + kg) ^ sx) * 8;
            f16x8 a_[4], b_[4];
            #pragma unroll
            for (int mi = 0; mi < 4; ++mi)
                a_[mi] = *(const f16x8*)&bufc[arow + mi * 1024 + so];
            #pragma unroll
            for (int ni = 0; ni < 4; ++ni)
                b_[ni] = *(const f16x8*)&bufc[8192 + brow + ni * 1024 + so];
            #pragma unroll
            for (int mi = 0; mi < 4; ++mi)
                #pragma unroll
                for (int ni = 0; ni < 4; ++ni)
                    acc[mi][ni] = __builtin_amdgcn_mfma_f32_16x16x32_f16(
                        a_[mi], b_[ni], acc[mi][ni], 0, 0, 0);
        }
        __syncthreads();   // buf[cur] reads done; buf[cur^1] writes drained
    }

    if (which == 2) {
        #pragma unroll
        for (int mi = 0; mi < 4; ++mi) {
            #pragma unroll
            for (int ni = 0; ni < 4; ++ni) {
                const int n    = n0 + wc * 64 + ni * 16 + colL;
                const int mrow = m0 + wr * 64 + mi * 16 + kg * 4;
                const float bn = bias[n];
                const int bb = mrow >> 9;
                const int ss = mrow & (S_ - 1);
                const int hh = n >> 6;
                const int dd = n & (D_ - 1);
                ushort4 vh;
                vh.x = f2h(acc[mi][ni][0] + bn);
                vh.y = f2h(acc[mi][ni][1] + bn);
                vh.z = f2h(acc[mi][ni][2] + bn);
                vh.w = f2h(acc[mi][ni][3] + bn);
                *(ushort4*)&Vth[(((size_t)bb * H_ + hh) * D_ + dd) * S_ + ss] = vh;
            }
        }
    } else {
        u16t* __restrict__ Oh = (which == 0) ? Qh : Kh;
        float* LF = (float*)SM;
        float bn4[4];
        #pragma unroll
        for (int ni = 0; ni < 4; ++ni) bn4[ni] = bias[n0 + wc * 64 + ni * 16 + colL];

        const int er  = tid >> 3;
        const int ecc = (tid & 7) * 16;
        const int ehh = (n0 + ecc) >> 6;
        const int edd = ecc & 63;
        const int mrowE = m0 + (er >> 4) * 64 + (er & 15);

        #pragma unroll
        for (int mi = 0; mi < 4; ++mi) {
            __syncthreads();
            #pragma unroll
            for (int ni = 0; ni < 4; ++ni)
                #pragma unroll
                for (int j = 0; j < 4; ++j)
                    LF[(wr * 16 + kg * 4 + j) * 130 + wc * 64 + ni * 16 + colL] =
                        acc[mi][ni][j] + bn4[ni];
            __syncthreads();

            const int mrow = mrowE + mi * 16;
            const int bb = mrow >> 9;
            const int ss = mrow & (S_ - 1);
            __align__(16) u16t hv[16];
            #pragma unroll
            for (int u = 0; u < 16; u += 4) {
                float4 v = *(const float4*)&LF[er * 130 + ecc + u];
                hv[u + 0] = f2h(v.x);
                hv[u + 1] = f2h(v.y);
                hv[u + 2] = f2h(v.z);
                hv[u + 3] = f2h(v.w);
            }
            const size_t off = (((size_t)bb * H_ + ehh) * S_ + ss) * D_ + edd;
            *(s16x8*)&Oh[off]     = *(const s16x8*)&hv[0];
            *(s16x8*)&Oh[off + 8] = *(const s16x8*)&hv[8];
        }
    }
}

// ---------------------------------------------------------------------------
// MFMA flash attention v4: v3 + defer-max (T13, THR=8) + early ge/mask
// register prefetch + s_setprio around MFMA clusters (T5).
// ---------------------------------------------------------------------------
__global__ __launch_bounds__(512) void attn_mfma_kernel(
    const u16t* __restrict__ Qhg, const u16t* __restrict__ Khg,
    const u16t* __restrict__ Vhg,
    const int*  __restrict__ ge,  const float* __restrict__ mask,
    const float* __restrict__ dpk, const float* __restrict__ dpv,
    float* __restrict__ out)
{
    __shared__ __align__(16) u16t Q_s[128 * 64];   // 16 KB
    __shared__ __align__(16) u16t K_s[64 * 64];    // 8 KB
    __shared__ __align__(16) u16t V_s[64 * 64];    // 8 KB
    __shared__ __align__(16) u16t P_s[8 * 2304];   // 36 KB

    const int tid  = threadIdx.x;
    const int lane = tid & 63;
    const int wq   = tid >> 6;
    const int c    = lane & 15;
    const int g    = lane >> 4;
    const int sx   = c & 7;
    const int bid  = blockIdx.x;
    const int bh   = bid >> 2;
    const int q0   = (bid & 3) * 128;
    const int b    = bh >> 4;
    const int h    = bh & (H_ - 1);

    u16t* Pw = &P_s[wq * 2304];

    {
        const u16t* qbase = Qhg + ((size_t)bh * S_ + q0) * D_;
        #pragma unroll
        for (int t = 0; t < 2; ++t) {
            const int chk = tid + t * 512;
            const int r = chk >> 3, s = chk & 7;
            *(s16x8*)&Q_s[r * 64 + ((s ^ (r & 7)) << 3)] =
                *(const s16x8*)&qbase[chk * 8];
        }
    }

    const int r_   = tid >> 3;
    const int s_   = tid & 7;
    const int ldso = r_ * 64 + ((s_ ^ (r_ & 7)) << 3);
    const u16t* kgp = &Khg[((size_t)bh * S_ + r_) * D_ + s_ * 8];
    const u16t* vgp = &Vhg[((size_t)bh * D_ + r_) * S_ + s_ * 8];

    {
        s16x8 kr = *(const s16x8*)kgp;
        s16x8 vr = *(const s16x8*)vgp;
        *(s16x8*)&K_s[ldso] = kr;
        *(s16x8*)&V_s[ldso] = vr;
    }
    __syncthreads();

    // ---- t_r = q . dp_k[r]: per-lane partial dot + xor-16/32 ----
    float tq1, tq2;
    {
        const int qrow = wq * 16 + c;
        float a1 = 0.f, a2 = 0.f;
        #pragma unroll
        for (int t = 0; t < 2; ++t) {
            const int slot = 2 * g + t;
            const f16x8 qv8 = *(const f16x8*)&Q_s[qrow * 64 + ((slot ^ sx) << 3)];
            const int dbase = slot * 8;
            #pragma unroll
            for (int i = 0; i < 8; ++i) {
                const float qv = (float)qv8[i];
                a1 = fmaf(qv, dpk[D_ + dbase + i], a1);
                a2 = fmaf(qv, dpk[2 * D_ + dbase + i], a2);
            }
        }
        a1 += __shfl_xor(a1, 16); a1 += __shfl_xor(a1, 32);
        a2 += __shfl_xor(a2, 16); a2 += __shfl_xor(a2, 32);
        tq1 = a1; tq2 = a2;
    }

    const size_t geoff = ((size_t)b * S_ + q0 + wq * 16 + c) * S_;
    const float* mrow = &mask[(size_t)b * S_];

    float mrun = -INFINITY, lrun = 0.f, w1 = 0.f, w2 = 0.f;
    f32x4 ctx4[4];
    #pragma unroll
    for (int mi = 0; mi < 4; ++mi)
        #pragma unroll
        for (int e = 0; e < 4; ++e) ctx4[mi][e] = 0.f;

    for (int kt = 0; kt < S_ / 64; ++kt) {
        const int k0 = kt * 64;

        // T14: next-tile K/V loads issued before compute
        s16x8 krB, vrB;
        if (kt < S_ / 64 - 1) {
            krB = *(const s16x8*)(kgp + (size_t)(k0 + 64) * D_);
            vrB = *(const s16x8*)(vgp + (k0 + 64));
        }
        // early ge/mask loads for THIS tile (hide under QK^T)
        int4   gc4[4];
        float4 mk4[4];
        #pragma unroll
        for (int mi = 0; mi < 4; ++mi) {
            gc4[mi] = *(const int4*)&ge[geoff + k0 + mi * 16 + g * 4];
            mk4[mi] = *(const float4*)&mrow[k0 + mi * 16 + g * 4];
        }

        // ---- QK^T (transposed) ----
        f32x4 s4[4];
        #pragma unroll
        for (int mi = 0; mi < 4; ++mi)
            #pragma unroll
            for (int e = 0; e < 4; ++e) s4[mi][e] = 0.f;

        __builtin_amdgcn_s_setprio(1);
        #pragma unroll
        for (int ks = 0; ks < 2; ++ks) {
            const int so = ((g + 4 * ks) ^ sx) << 3;
            const f16x8 qh_ = *(const f16x8*)&Q_s[(wq * 16 + c) * 64 + so];
            #pragma unroll
            for (int mi = 0; mi < 4; ++mi) {
                const f16x8 kh_ = *(const f16x8*)&K_s[(mi * 16 + c) * 64 + so];
                s4[mi] = __builtin_amdgcn_mfma_f32_16x16x32_f16(kh_, qh_, s4[mi], 0, 0, 0);
            }
        }
        __builtin_amdgcn_s_setprio(0);

        // ---- relation + mask + online softmax ----
        float sv[4][4];
        int   gcode[4][4];
        float tmax = -INFINITY;
        #pragma unroll
        for (int mi = 0; mi < 4; ++mi) {
            const int   gg[4] = {gc4[mi].x, gc4[mi].y, gc4[mi].z, gc4[mi].w};
            const float mm[4] = {mk4[mi].x, mk4[mi].y, mk4[mi].z, mk4[mi].w};
            #pragma unroll
            for (int j = 0; j < 4; ++j) {
                const float t = (gg[j] == 1) ? tq1 : (gg[j] == 2) ? tq2 : 0.f;
                const float x = fmaf(s4[mi][j], 0.125f, t + mm[j]);
                sv[mi][j] = x;
                gcode[mi][j] = gg[j];
                tmax = fmaxf(tmax, x);
            }
        }
        tmax = fmaxf(tmax, __shfl_xor(tmax, 16));
        tmax = fmaxf(tmax, __shfl_xor(tmax, 32));

        // T13 defer-max: skip rescale if tile max within THR of running max
        if (!__all(tmax - mrun <= 8.0f)) {
            const float mn    = fmaxf(mrun, tmax);
            const float alpha = __expf(mrun - mn);
            mrun = mn;
            lrun *= alpha; w1 *= alpha; w2 *= alpha;
            #pragma unroll
            for (int mi = 0; mi < 4; ++mi) ctx4[mi] *= alpha;
        }

        float rs = 0.f, rb1 = 0.f, rb2 = 0.f;
        #pragma unroll
        for (int mi = 0; mi < 4; ++mi)
            #pragma unroll
            for (int j = 0; j < 4; ++j) {
                const float e = __expf(sv[mi][j] - mrun);
                sv[mi][j] = e;
                rs += e;
                rb1 += (gcode[mi][j] == 1) ? e : 0.f;
                rb2 += (gcode[mi][j] == 2) ? e : 0.f;
            }
        rs  += __shfl_xor(rs, 16);  rs  += __shfl_xor(rs, 32);
        rb1 += __shfl_xor(rb1, 16); rb1 += __shfl_xor(rb1, 32);
        rb2 += __shfl_xor(rb2, 16); rb2 += __shfl_xor(rb2, 32);

        lrun += rs;
        w1   += rb1;
        w2   += rb2;

        // ---- P -> fp16, wave-local LDS, pitch 64 + XOR slot swizzle ----
        #pragma unroll
        for (int mi = 0; mi < 4; ++mi) {
            ushort4 ph;
            ph.x = f2h(sv[mi][0]);
            ph.y = f2h(sv[mi][1]);
            ph.z = f2h(sv[mi][2]);
            ph.w = f2h(sv[mi][3]);
            const int slotp = (2 * mi + (g >> 1)) ^ sx;
            *(ushort4*)&Pw[c * 64 + slotp * 8 + (g & 1) * 4] = ph;
        }

        // ---- PV ----
        __builtin_amdgcn_s_setprio(1);
        #pragma unroll
        for (int ks = 0; ks < 2; ++ks) {
            const int so = ((g + 4 * ks) ^ sx) << 3;
            const f16x8 ph_ = *(const f16x8*)&Pw[c * 64 + so];
            #pragma unroll
            for (int mi = 0; mi < 4; ++mi) {
                const f16x8 vh_ = *(const f16x8*)&V_s[(mi * 16 + c) * 64 + so];
                ctx4[mi] = __builtin_amdgcn_mfma_f32_16x16x32_f16(vh_, ph_, ctx4[mi], 0, 0, 0);
            }
        }
        __builtin_amdgcn_s_setprio(0);
        __syncthreads();

        if (kt < S_ / 64 - 1) {
            *(s16x8*)&K_s[ldso] = krB;
            *(s16x8*)&V_s[ldso] = vrB;
            __syncthreads();
        }
    }

    // ---- epilogue: normalize + relation-value; transpose via LDS ----
    const float inv = 1.0f / lrun;
    float* tb = (float*)&P_s[wq * 2304];
    #pragma unroll
    for (int mi = 0; mi < 4; ++mi) {
        const float4 dk1 = *(const float4*)&dpv[D_ + mi * 16 + g * 4];
        const float4 dk2 = *(const float4*)&dpv[2 * D_ + mi * 16 + g * 4];
        const float a1[4] = {dk1.x, dk1.y, dk1.z, dk1.w};
        const float a2[4] = {dk2.x, dk2.y, dk2.z, dk2.w};
        #pragma unroll
        for (int j = 0; j < 4; ++j) {
            const float val = (ctx4[mi][j] + w1 * a1[j] + w2 * a2[j]) * inv;
            tb[(mi * 16 + g * 4 + j) * 17 + c] = val;
        }
    }
    __syncthreads();
    #pragma unroll
    for (int qq = 0; qq < 16; ++qq)
        out[((size_t)b * S_ + q0 + wq * 16 + qq) * (H_ * D_) + h * D_ + lane] =
            tb[lane * 17 + qq];
}

extern "C" void kernel_launch(void* const* d_in, const int* in_sizes, int n_in,
                              void* d_out, int out_size, void* d_ws, size_t ws_size,
                              hipStream_t stream)
{
    const float* hs   = (const float*)d_in[0];
    const float* mask = (const float*)d_in[1];
    const int*   ge   = (const int*)d_in[2];
    const float* Wq   = (const float*)d_in[3];
    const float* bq   = (const float*)d_in[4];
    const float* Wk   = (const float*)d_in[5];
    const float* bk   = (const float*)d_in[6];
    const float* Wv   = (const float*)d_in[7];
    const float* bv   = (const float*)d_in[8];
    const float* dpk  = (const float*)d_in[9];
    const float* dpv  = (const float*)d_in[10];
    float* out = (float*)d_out;

    const size_t per = (size_t)B_ * H_ * S_ * D_;   // 4,194,304
    const size_t nX  = (size_t)B_ * S_ * HID;       // 4,194,304
    const size_t nW  = (size_t)HID * HID;           // 1,048,576

    u16t* base = (u16t*)d_ws;
    u16t* Qh  = base;
    u16t* Kh  = Qh  + per;
    u16t* Vth = Kh  + per;
    u16t* Xhi = Vth + per;
    u16t* Whi = Xhi + nX;

    const int nConv = (int)((nX + 3 * nW) / 4);
    conv_all_kernel<<<nConv / 256, 256, 0, stream>>>(hs, Wq, Wk, Wv, Xhi, Whi);

    dim3 gridG(HID / 128, (B_ * S_) / 128, 3);
    qkv_mfma_kernel<<<gridG, dim3(256), 0, stream>>>(
        Xhi, Whi, bq, bk, bv, Qh, Kh, Vth);

    dim3 gridB(B_ * H_ * (S_ / 128));
    attn_mfma_kernel<<<gridB, dim3(512), 0, stream>>>(
        Qh, Kh, Vth, ge, mask, dpk, dpv, out);
}

// Round 12
// 78.016 us; speedup vs baseline: 2.5192x; 1.0209x over previous
//
#include <hip/hip_runtime.h>
#include <hip/hip_bf16.h>
#include <cstddef>

#define B_  8
#define S_  512
#define HID 1024
#define H_  16
#define D_  64

typedef float f32x4 __attribute__((ext_vector_type(4)));
typedef _Float16 f16x8 __attribute__((ext_vector_type(8)));
typedef short s16x8 __attribute__((ext_vector_type(8)));
typedef unsigned short u16t;

__device__ __forceinline__ u16t f2h(float v) {
    return __builtin_bit_cast(u16t, (_Float16)v);
}
__device__ __forceinline__ float h2f(u16t u) {
    return (float)__builtin_bit_cast(_Float16, u);
}

// async global->LDS, 16B per lane (dest = wave-uniform base + lane*16)
__device__ __forceinline__ void gll16(const u16t* g, u16t* l) {
    __builtin_amdgcn_global_load_lds(
        (const __attribute__((address_space(1))) unsigned int*)(const void*)g,
        (__attribute__((address_space(3))) unsigned int*)(void*)l, 16, 0, 0);
}

// one fused conversion kernel: X (f32->fp16) then Wq,Wk,Wv
__global__ __launch_bounds__(256) void conv_all_kernel(
    const float* __restrict__ X,
    const float* __restrict__ Wq, const float* __restrict__ Wk,
    const float* __restrict__ Wv,
    u16t* __restrict__ Xh, u16t* __restrict__ Wh)
{
    const int nX4 = (B_ * S_ * HID) / 4;
    const int nW4 = (HID * HID) / 4;
    int i = blockIdx.x * 256 + threadIdx.x;
    const float* src;
    u16t* dst;
    int off;
    if (i < nX4)                { src = X;  dst = Xh;                         off = i; }
    else if (i < nX4 + nW4)     { src = Wq; dst = Wh;                         off = i - nX4; }
    else if (i < nX4 + 2 * nW4) { src = Wk; dst = Wh + (size_t)HID * HID;     off = i - nX4 - nW4; }
    else                        { src = Wv; dst = Wh + (size_t)2 * HID * HID; off = i - nX4 - 2 * nW4; }
    float4 x = ((const float4*)src)[off];
    ushort4 h;
    h.x = f2h(x.x);
    h.y = f2h(x.y);
    h.z = f2h(x.z);
    h.w = f2h(x.w);
    ((ushort4*)dst)[off] = h;
}

// ---------------------------------------------------------------------------
// QKV projection, pure fp16 MFMA, double-buffered (unchanged from round 11).
// ---------------------------------------------------------------------------
__global__ __launch_bounds__(256) void qkv_mfma_kernel(
    const u16t* __restrict__ Xhi, const u16t* __restrict__ Whi,
    const float* __restrict__ bq, const float* __restrict__ bk,
    const float* __restrict__ bv,
    u16t* __restrict__ Qh, u16t* __restrict__ Kh, u16t* __restrict__ Vth)
{
    const int which = blockIdx.z;
    const u16t* __restrict__ WhiB = Whi + (size_t)which * (HID * HID);
    const float* __restrict__ bias = (which == 0) ? bq : (which == 1) ? bk : bv;

    __shared__ __align__(16) u16t SM[2 * 16384];

    const int tid  = threadIdx.x;
    const int lane = tid & 63;
    const int wv_  = tid >> 6;
    const int wr   = wv_ >> 1;
    const int wc   = wv_ & 1;
    const int m0   = blockIdx.y * 128;
    const int n0   = blockIdx.x * 128;

    f32x4 acc[4][4];
    #pragma unroll
    for (int mi = 0; mi < 4; ++mi)
        #pragma unroll
        for (int ni = 0; ni < 4; ++ni)
            #pragma unroll
            for (int e = 0; e < 4; ++e) acc[mi][ni][e] = 0.0f;

    const int rowB0 = wv_ * 32 + (lane >> 3);
    const int ch    = (lane & 7) ^ (rowB0 & 7);
    const size_t aof = (size_t)(m0 + rowB0) * HID + ch * 8;
    const size_t bof = (size_t)(n0 + rowB0) * HID + ch * 8;
    const int ldsA = (wv_ * 32) * 64;

    const int colL = lane & 15;
    const int kg   = lane >> 4;
    const int sx   = colL & 7;
    const int arow = (wr * 64 + colL) * 64;
    const int brow = (wc * 64 + colL) * 64;

    #pragma unroll
    for (int s = 0; s < 4; ++s) {
        gll16(&Xhi [aof + (size_t)(s * 8) * HID], SM + ldsA + s * 512);
        gll16(&WhiB[bof + (size_t)(s * 8) * HID], SM + 8192 + ldsA + s * 512);
    }
    __syncthreads();

    for (int k0 = 0; k0 < HID; k0 += 64) {
        const int cur = (k0 >> 6) & 1;
        u16t* const bufc = SM + cur * 16384;
        if (k0 + 64 < HID) {
            u16t* const bufn = SM + (cur ^ 1) * 16384;
            #pragma unroll
            for (int s = 0; s < 4; ++s) {
                gll16(&Xhi [aof + k0 + 64 + (size_t)(s * 8) * HID], bufn + ldsA + s * 512);
                gll16(&WhiB[bof + k0 + 64 + (size_t)(s * 8) * HID], bufn + 8192 + ldsA + s * 512);
            }
        }

        #pragma unroll
        for (int ks = 0; ks < 2; ++ks) {
            const int so = ((ks * 4 + kg) ^ sx) * 8;
            f16x8 a_[4], b_[4];
            #pragma unroll
            for (int mi = 0; mi < 4; ++mi)
                a_[mi] = *(const f16x8*)&bufc[arow + mi * 1024 + so];
            #pragma unroll
            for (int ni = 0; ni < 4; ++ni)
                b_[ni] = *(const f16x8*)&bufc[8192 + brow + ni * 1024 + so];
            #pragma unroll
            for (int mi = 0; mi < 4; ++mi)
                #pragma unroll
                for (int ni = 0; ni < 4; ++ni)
                    acc[mi][ni] = __builtin_amdgcn_mfma_f32_16x16x32_f16(
                        a_[mi], b_[ni], acc[mi][ni], 0, 0, 0);
        }
        __syncthreads();
    }

    if (which == 2) {
        #pragma unroll
        for (int mi = 0; mi < 4; ++mi) {
            #pragma unroll
            for (int ni = 0; ni < 4; ++ni) {
                const int n    = n0 + wc * 64 + ni * 16 + colL;
                const int mrow = m0 + wr * 64 + mi * 16 + kg * 4;
                const float bn = bias[n];
                const int bb = mrow >> 9;
                const int ss = mrow & (S_ - 1);
                const int hh = n >> 6;
                const int dd = n & (D_ - 1);
                ushort4 vh;
                vh.x = f2h(acc[mi][ni][0] + bn);
                vh.y = f2h(acc[mi][ni][1] + bn);
                vh.z = f2h(acc[mi][ni][2] + bn);
                vh.w = f2h(acc[mi][ni][3] + bn);
                *(ushort4*)&Vth[(((size_t)bb * H_ + hh) * D_ + dd) * S_ + ss] = vh;
            }
        }
    } else {
        u16t* __restrict__ Oh = (which == 0) ? Qh : Kh;
        float* LF = (float*)SM;
        float bn4[4];
        #pragma unroll
        for (int ni = 0; ni < 4; ++ni) bn4[ni] = bias[n0 + wc * 64 + ni * 16 + colL];

        const int er  = tid >> 3;
        const int ecc = (tid & 7) * 16;
        const int ehh = (n0 + ecc) >> 6;
        const int edd = ecc & 63;
        const int mrowE = m0 + (er >> 4) * 64 + (er & 15);

        #pragma unroll
        for (int mi = 0; mi < 4; ++mi) {
            __syncthreads();
            #pragma unroll
            for (int ni = 0; ni < 4; ++ni)
                #pragma unroll
                for (int j = 0; j < 4; ++j)
                    LF[(wr * 16 + kg * 4 + j) * 130 + wc * 64 + ni * 16 + colL] =
                        acc[mi][ni][j] + bn4[ni];
            __syncthreads();

            const int mrow = mrowE + mi * 16;
            const int bb = mrow >> 9;
            const int ss = mrow & (S_ - 1);
            __align__(16) u16t hv[16];
            #pragma unroll
            for (int u = 0; u < 16; u += 4) {
                float4 v = *(const float4*)&LF[er * 130 + ecc + u];
                hv[u + 0] = f2h(v.x);
                hv[u + 1] = f2h(v.y);
                hv[u + 2] = f2h(v.z);
                hv[u + 3] = f2h(v.w);
            }
            const size_t off = (((size_t)bb * H_ + ehh) * S_ + ss) * D_ + edd;
            *(s16x8*)&Oh[off]     = *(const s16x8*)&hv[0];
            *(s16x8*)&Oh[off + 8] = *(const s16x8*)&hv[8];
        }
    }
}

// ---------------------------------------------------------------------------
// MFMA flash attention v5:
//  - Q fragments in REGISTERS (lane only needs slots g and g+4 of its q-row)
//    -> no Q_s (−16KB LDS), no Q ds_reads, shuffle-light t1/t2.
//  - K/V double-buffered in LDS -> ONE barrier per k-tile (was 2).
//  - LDS 48KB: K0|V0|K1|V1 (32KB) + per-wave P (16KB); epilogue transpose
//    aliases the dead K/V region (34.8KB needed <= 48KB).
//  - keeps: T14 early loads, T13 defer-max, T5 setprio, XOR swizzles.
// ---------------------------------------------------------------------------
__global__ __launch_bounds__(512) void attn_mfma_kernel(
    const u16t* __restrict__ Qhg, const u16t* __restrict__ Khg,
    const u16t* __restrict__ Vhg,
    const int*  __restrict__ ge,  const float* __restrict__ mask,
    const float* __restrict__ dpk, const float* __restrict__ dpv,
    float* __restrict__ out)
{
    // u16 layout: K0 @0, V0 @4096, K1 @8192, V1 @12288, P @16384 (+wq*1024)
    __shared__ __align__(16) u16t SM[24576];   // 48 KB

    const int tid  = threadIdx.x;
    const int lane = tid & 63;
    const int wq   = tid >> 6;
    const int c    = lane & 15;
    const int g    = lane >> 4;
    const int sx   = c & 7;
    const int bid  = blockIdx.x;
    const int bh   = bid >> 2;
    const int q0   = (bid & 3) * 128;
    const int b    = bh >> 4;
    const int h    = bh & (H_ - 1);

    u16t* Pw = SM + 16384 + wq * 1024;

    // ---- Q fragments straight to registers ----
    const int qrow = q0 + wq * 16 + c;
    const size_t qoff = ((size_t)bh * S_ + qrow) * D_;
    const f16x8 qA = *(const f16x8*)&Qhg[qoff + g * 8];        // slot g   (ks=0)
    const f16x8 qB = *(const f16x8*)&Qhg[qoff + (g + 4) * 8];  // slot g+4 (ks=1)

    // ---- t1/t2: 16-elem partial dot + xor 16/32 (g-group reduce) ----
    float tq1, tq2;
    {
        float a1 = 0.f, a2 = 0.f;
        #pragma unroll
        for (int i = 0; i < 8; ++i) {
            const float x0 = (float)qA[i];
            const float x1 = (float)qB[i];
            a1 = fmaf(x0, dpk[D_ + g * 8 + i], a1);
            a1 = fmaf(x1, dpk[D_ + (g + 4) * 8 + i], a1);
            a2 = fmaf(x0, dpk[2 * D_ + g * 8 + i], a2);
            a2 = fmaf(x1, dpk[2 * D_ + (g + 4) * 8 + i], a2);
        }
        a1 += __shfl_xor(a1, 16); a1 += __shfl_xor(a1, 32);
        a2 += __shfl_xor(a2, 16); a2 += __shfl_xor(a2, 32);
        tq1 = a1; tq2 = a2;
    }

    // K/V staging mapping (1 x 16B chunk each per thread per tile)
    const int r_   = tid >> 3;
    const int s_   = tid & 7;
    const int ldso = r_ * 64 + ((s_ ^ (r_ & 7)) << 3);
    const u16t* kgp = &Khg[((size_t)bh * S_ + r_) * D_ + s_ * 8];
    const u16t* vgp = &Vhg[((size_t)bh * D_ + r_) * S_ + s_ * 8];

    // prologue: load tile 0 into regs
    s16x8 krS = *(const s16x8*)kgp;
    s16x8 vrS = *(const s16x8*)vgp;

    const size_t geoff = ((size_t)b * S_ + qrow) * S_;
    const float* mrow = &mask[(size_t)b * S_];

    float mrun = -INFINITY, lrun = 0.f, w1 = 0.f, w2 = 0.f;
    f32x4 ctx4[4];
    #pragma unroll
    for (int mi = 0; mi < 4; ++mi)
        #pragma unroll
        for (int e = 0; e < 4; ++e) ctx4[mi][e] = 0.f;

    for (int kt = 0; kt < S_ / 64; ++kt) {
        const int k0 = kt * 64;
        const int bufo = (kt & 1) << 13;       // 0 / 8192 u16
        u16t* const Kb = SM + bufo;
        u16t* const Vb = SM + bufo + 4096;

        // (1) commit staged tile kt into its buffer
        *(s16x8*)&Kb[ldso] = krS;
        *(s16x8*)&Vb[ldso] = vrS;

        // (2) issue tile kt+1's global loads (T14: hide under compute)
        if (kt < S_ / 64 - 1) {
            krS = *(const s16x8*)(kgp + (size_t)(k0 + 64) * D_);
            vrS = *(const s16x8*)(vgp + (k0 + 64));
        }
        // early ge/mask loads for THIS tile
        int4   gc4[4];
        float4 mk4[4];
        #pragma unroll
        for (int mi = 0; mi < 4; ++mi) {
            gc4[mi] = *(const int4*)&ge[geoff + k0 + mi * 16 + g * 4];
            mk4[mi] = *(const float4*)&mrow[k0 + mi * 16 + g * 4];
        }

        // (3) single barrier: tile kt visible to all waves
        __syncthreads();

        // (4) QK^T (transposed): lane holds k = mi*16+g*4+j for q-row `qrow`
        f32x4 s4[4];
        #pragma unroll
        for (int mi = 0; mi < 4; ++mi)
            #pragma unroll
            for (int e = 0; e < 4; ++e) s4[mi][e] = 0.f;

        __builtin_amdgcn_s_setprio(1);
        #pragma unroll
        for (int ks = 0; ks < 2; ++ks) {
            const int so = ((g + 4 * ks) ^ sx) << 3;
            const f16x8 qh_ = ks ? qB : qA;
            #pragma unroll
            for (int mi = 0; mi < 4; ++mi) {
                const f16x8 kh_ = *(const f16x8*)&Kb[(mi * 16 + c) * 64 + so];
                s4[mi] = __builtin_amdgcn_mfma_f32_16x16x32_f16(kh_, qh_, s4[mi], 0, 0, 0);
            }
        }
        __builtin_amdgcn_s_setprio(0);

        // relation + mask + online softmax
        float sv[4][4];
        int   gcode[4][4];
        float tmax = -INFINITY;
        #pragma unroll
        for (int mi = 0; mi < 4; ++mi) {
            const int   gg[4] = {gc4[mi].x, gc4[mi].y, gc4[mi].z, gc4[mi].w};
            const float mm[4] = {mk4[mi].x, mk4[mi].y, mk4[mi].z, mk4[mi].w};
            #pragma unroll
            for (int j = 0; j < 4; ++j) {
                const float t = (gg[j] == 1) ? tq1 : (gg[j] == 2) ? tq2 : 0.f;
                const float x = fmaf(s4[mi][j], 0.125f, t + mm[j]);
                sv[mi][j] = x;
                gcode[mi][j] = gg[j];
                tmax = fmaxf(tmax, x);
            }
        }
        tmax = fmaxf(tmax, __shfl_xor(tmax, 16));
        tmax = fmaxf(tmax, __shfl_xor(tmax, 32));

        // T13 defer-max
        if (!__all(tmax - mrun <= 8.0f)) {
            const float mn    = fmaxf(mrun, tmax);
            const float alpha = __expf(mrun - mn);
            mrun = mn;
            lrun *= alpha; w1 *= alpha; w2 *= alpha;
            #pragma unroll
            for (int mi = 0; mi < 4; ++mi) ctx4[mi] *= alpha;
        }

        float rs = 0.f, rb1 = 0.f, rb2 = 0.f;
        #pragma unroll
        for (int mi = 0; mi < 4; ++mi)
            #pragma unroll
            for (int j = 0; j < 4; ++j) {
                const float e = __expf(sv[mi][j] - mrun);
                sv[mi][j] = e;
                rs += e;
                rb1 += (gcode[mi][j] == 1) ? e : 0.f;
                rb2 += (gcode[mi][j] == 2) ? e : 0.f;
            }
        rs  += __shfl_xor(rs, 16);  rs  += __shfl_xor(rs, 32);
        rb1 += __shfl_xor(rb1, 16); rb1 += __shfl_xor(rb1, 32);
        rb2 += __shfl_xor(rb2, 16); rb2 += __shfl_xor(rb2, 32);

        lrun += rs;
        w1   += rb1;
        w2   += rb2;

        // P -> fp16, wave-local LDS, pitch 64 + XOR slot swizzle
        #pragma unroll
        for (int mi = 0; mi < 4; ++mi) {
            ushort4 ph;
            ph.x = f2h(sv[mi][0]);
            ph.y = f2h(sv[mi][1]);
            ph.z = f2h(sv[mi][2]);
            ph.w = f2h(sv[mi][3]);
            const int slotp = (2 * mi + (g >> 1)) ^ sx;
            *(ushort4*)&Pw[c * 64 + slotp * 8 + (g & 1) * 4] = ph;
        }

        // PV
        __builtin_amdgcn_s_setprio(1);
        #pragma unroll
        for (int ks = 0; ks < 2; ++ks) {
            const int so = ((g + 4 * ks) ^ sx) << 3;
            const f16x8 ph_ = *(const f16x8*)&Pw[c * 64 + so];
            #pragma unroll
            for (int mi = 0; mi < 4; ++mi) {
                const f16x8 vh_ = *(const f16x8*)&Vb[(mi * 16 + c) * 64 + so];
                ctx4[mi] = __builtin_amdgcn_mfma_f32_16x16x32_f16(vh_, ph_, ctx4[mi], 0, 0, 0);
            }
        }
        __builtin_amdgcn_s_setprio(0);
        // no trailing barrier: next iteration writes the OTHER buffer,
        // and its single barrier orders write->read for tile kt+1.
    }

    // ---- epilogue: all waves done with K/V before aliasing SM as tb ----
    __syncthreads();
    const float inv = 1.0f / lrun;
    float* tb = (float*)SM + wq * 1088;    // 64x17 f32 = 4352B per wave
    #pragma unroll
    for (int mi = 0; mi < 4; ++mi) {
        const float4 dk1 = *(const float4*)&dpv[D_ + mi * 16 + g * 4];
        const float4 dk2 = *(const float4*)&dpv[2 * D_ + mi * 16 + g * 4];
        const float a1[4] = {dk1.x, dk1.y, dk1.z, dk1.w};
        const float a2[4] = {dk2.x, dk2.y, dk2.z, dk2.w};
        #pragma unroll
        for (int j = 0; j < 4; ++j) {
            const float val = (ctx4[mi][j] + w1 * a1[j] + w2 * a2[j]) * inv;
            tb[(mi * 16 + g * 4 + j) * 17 + c] = val;
        }
    }
    __syncthreads();
    #pragma unroll
    for (int qq = 0; qq < 16; ++qq)
        out[((size_t)b * S_ + q0 + wq * 16 + qq) * (H_ * D_) + h * D_ + lane] =
            tb[lane * 17 + qq];
}

extern "C" void kernel_launch(void* const* d_in, const int* in_sizes, int n_in,
                              void* d_out, int out_size, void* d_ws, size_t ws_size,
                              hipStream_t stream)
{
    const float* hs   = (const float*)d_in[0];
    const float* mask = (const float*)d_in[1];
    const int*   ge   = (const int*)d_in[2];
    const float* Wq   = (const float*)d_in[3];
    const float* bq   = (const float*)d_in[4];
    const float* Wk   = (const float*)d_in[5];
    const float* bk   = (const float*)d_in[6];
    const float* Wv   = (const float*)d_in[7];
    const float* bv   = (const float*)d_in[8];
    const float* dpk  = (const float*)d_in[9];
    const float* dpv  = (const float*)d_in[10];
    float* out = (float*)d_out;

    const size_t per = (size_t)B_ * H_ * S_ * D_;   // 4,194,304
    const size_t nX  = (size_t)B_ * S_ * HID;       // 4,194,304
    const size_t nW  = (size_t)HID * HID;           // 1,048,576

    u16t* base = (u16t*)d_ws;
    u16t* Qh  = base;
    u16t* Kh  = Qh  + per;
    u16t* Vth = Kh  + per;
    u16t* Xhi = Vth + per;
    u16t* Whi = Xhi + nX;

    const int nConv = (int)((nX + 3 * nW) / 4);
    conv_all_kernel<<<nConv / 256, 256, 0, stream>>>(hs, Wq, Wk, Wv, Xhi, Whi);

    dim3 gridG(HID / 128, (B_ * S_) / 128, 3);
    qkv_mfma_kernel<<<gridG, dim3(256), 0, stream>>>(
        Xhi, Whi, bq, bk, bv, Qh, Kh, Vth);

    dim3 gridB(B_ * H_ * (S_ / 128));
    attn_mfma_kernel<<<gridB, dim3(512), 0, stream>>>(
        Qh, Kh, Vth, ge, mask, dpk, dpv, out);
}